// Round 14
// baseline (228.076 us; speedup 1.0000x reference)
//
#include <hip/hip_runtime.h>
#include <math.h>

#define B_  8
#define LQ  512
#define LK  512
#define DM  1024
#define NH  16
#define DK  64
constexpr float PADP = 10000.0f;

typedef short s16x8 __attribute__((ext_vector_type(8)));
typedef float f32x4 __attribute__((ext_vector_type(4)));

// ============================================================
// fp32 <-> bf16 helpers
// ============================================================
__device__ inline unsigned short f2b1(float f) {
    unsigned u = __float_as_uint(f);
    unsigned r = (u + 0x7fffu + ((u >> 16) & 1u)) >> 16;
    return (unsigned short)r;
}
__device__ inline float b2f1(unsigned short h) {
    return __uint_as_float(((unsigned)h) << 16);
}

// One launch converts q,k,v (4 slots of 1M elems each) + 4 weights.
__global__ __launch_bounds__(256) void f2b_all_kernel(
    const float* __restrict__ query, const float* __restrict__ key,
    const float* __restrict__ value,
    const float* __restrict__ Wq, const float* __restrict__ Wk,
    const float* __restrict__ Wv, const float* __restrict__ Wo,
    unsigned short* __restrict__ xq, unsigned short* __restrict__ xk,
    unsigned short* __restrict__ xv,
    unsigned short* __restrict__ wqb, unsigned short* __restrict__ wkb,
    unsigned short* __restrict__ wvb, unsigned short* __restrict__ wob)
{
    const int s = blockIdx.y;
    const float* src;
    unsigned short* dst;
    if (s < 4)       { src = query + ((size_t)s << 20);       dst = xq + ((size_t)s << 20); }
    else if (s < 8)  { src = key   + ((size_t)(s - 4) << 20); dst = xk + ((size_t)(s - 4) << 20); }
    else if (s < 12) { src = value + ((size_t)(s - 8) << 20); dst = xv + ((size_t)(s - 8) << 20); }
    else {
        const int w = s - 12;
        src = (w == 0) ? Wq : (w == 1) ? Wk : (w == 2) ? Wv : Wo;
        dst = (w == 0) ? wqb : (w == 1) ? wkb : (w == 2) ? wvb : wob;
    }
    const int i = blockIdx.x * 256 + threadIdx.x;
    const float4 v = *(const float4*)&src[(size_t)i * 4];
    ushort4 o;
    o.x = f2b1(v.x); o.y = f2b1(v.y); o.z = f2b1(v.z); o.w = f2b1(v.w);
    *(ushort4*)&dst[(size_t)i * 4] = o;
}

// ============================================================
// Position pipeline: 3 launches of daRow<PHASE>. D planes bf16.
// ============================================================
template <int PHASE>
__global__ __launch_bounds__(512) void daRow_kernel(
    const int* __restrict__ qlen, const int* __restrict__ klen,
    const float* __restrict__ pscale, const float* __restrict__ pbias,
    float* __restrict__ posQ,
    const float* __restrict__ posKin, float* __restrict__ posKout,
    const float* __restrict__ rsIn, const float* __restrict__ rdIn,
    const float* __restrict__ colSIn, const float* __restrict__ colDIn,
    float* __restrict__ rsOut, float* __restrict__ rdOut,
    float* __restrict__ colSOut, float* __restrict__ colDOut,
    unsigned short* __restrict__ Dplane)
{
    constexpr int NCH = 16, QC = LQ / NCH;
    __shared__ float kpl[LK];
    __shared__ float csp[8][LK], cdp[8][LK];
    const int chunk = blockIdx.x, b = blockIdx.y;
    const int t = threadIdx.x, w = t >> 6, lane = t & 63;

    float scale = 0.0f, bias = 0.0f;
    if (PHASE == 0) { scale = pscale[0]; bias = pbias[0]; }

    if (PHASE == 0) {
        const int kl = klen[b];
        const float Lf = (float)kl;
        const float step = (Lf > 1.0f) ? Lf / (Lf - 1.0f) : 0.0f;
        const float pos = (-Lf * 0.5f + (float)t * step) * scale + bias;
        const float kv = (t >= kl) ? PADP : pos;
        kpl[t] = kv;
        if (chunk == 0) posKout[b * LK + t] = kv;
    } else {
        float colsum = 0.0f, coldot = 0.0f;
#pragma unroll
        for (int c = 0; c < NCH; ++c) {
            colsum += colSIn[((size_t)b * NCH + c) * LK + t];
            coldot += colDIn[((size_t)b * NCH + c) * LK + t];
        }
        const float prev = posKin[b * LK + t];
        const float kv = (prev >= 1000.0f) ? PADP : coldot / fmaxf(colsum, 1e-9f);
        kpl[t] = kv;
        if (PHASE == 1 && chunk == 0) posKout[b * LK + t] = kv;
    }
    __syncthreads();

    float cs[8] = {0,0,0,0,0,0,0,0}, cd[8] = {0,0,0,0,0,0,0,0};
    unsigned short* Dbb = Dplane + (size_t)b * LQ * LK;

    for (int qi = chunk * QC + w; qi < chunk * QC + QC; qi += 8) {
        float qpv;
        if (PHASE == 0) {
            const int ql = qlen[b];
            const float Lf = (float)ql;
            const float step = (Lf > 1.0f) ? Lf / (Lf - 1.0f) : 0.0f;
            qpv = (qi >= ql) ? PADP : (-Lf * 0.5f + (float)qi * step) * scale + bias;
            if (lane == 0) posQ[b * LQ + qi] = qpv;
        } else {
            const float prev = posQ[b * LQ + qi];
            qpv = (prev >= 1000.0f) ? PADP
                : rdIn[b * LQ + qi] / fmaxf(rsIn[b * LQ + qi], 1e-9f);
            if (PHASE == 1 && lane == 0) posQ[b * LQ + qi] = qpv;
        }
        const bool qpad = (qpv >= 1000.0f);
        float rsum = 0.0f, rdot = 0.0f;
#pragma unroll
        for (int c = 0; c < 8; ++c) {
            const int k = lane + 64 * c;
            const float kpv = kpl[k];
            const float d = qpv - kpv;
            float e = (qpad || (kpv >= 1000.0f)) ? 0.0f : __expf(-0.5f * d * d);
            if (PHASE < 2) { rsum += e; rdot += e * kpv; cs[c] += e; cd[c] += e * qpv; }
            Dbb[(size_t)qi * LK + k] = f2b1(e);
        }
        if (PHASE < 2) {
#pragma unroll
            for (int o = 32; o > 0; o >>= 1) {
                rsum += __shfl_xor(rsum, o);
                rdot += __shfl_xor(rdot, o);
            }
            if (lane == 0) { rsOut[b * LQ + qi] = rsum; rdOut[b * LQ + qi] = rdot; }
        }
    }
    if (PHASE < 2) {
#pragma unroll
        for (int c = 0; c < 8; ++c) {
            csp[w][lane + 64 * c] = cs[c];
            cdp[w][lane + 64 * c] = cd[c];
        }
        __syncthreads();
        float s = 0.0f, dd = 0.0f;
        for (int ww = 0; ww < 8; ++ww) { s += csp[ww][t]; dd += cdp[ww][t]; }
        colSOut[((size_t)b * NCH + chunk) * LK + t] = s;
        colDOut[((size_t)b * NCH + chunk) * LK + t] = dd;
    }
}

// ============================================================
// bf16 transpose: in [Mn][Nn] -> out [Nn][Mn]
// ============================================================
__global__ __launch_bounds__(256) void transpose_bf16(
    const unsigned short* __restrict__ in, unsigned short* __restrict__ out,
    int Mn, int Nn)
{
    __shared__ unsigned short tile[64][65];
    const int m0 = blockIdx.y * 64, n0 = blockIdx.x * 64;
    const int t = threadIdx.x;
    const int r = t >> 3, c8 = (t & 7) * 8;
#pragma unroll
    for (int rr = 0; rr < 64; rr += 32) {
        const uint4 v = *(const uint4*)&in[(size_t)(m0 + r + rr) * Nn + n0 + c8];
        const unsigned short* pv = (const unsigned short*)&v;
#pragma unroll
        for (int j = 0; j < 8; ++j) tile[r + rr][c8 + j] = pv[j];
    }
    __syncthreads();
#pragma unroll
    for (int rr = 0; rr < 64; rr += 32) {
        unsigned short tmp[8];
#pragma unroll
        for (int j = 0; j < 8; ++j) tmp[j] = tile[c8 + j][r + rr];
        *(uint4*)&out[(size_t)(n0 + r + rr) * Mn + m0 + c8] = *(uint4*)tmp;
    }
}

// ============================================================
// bf16 MFMA GEMM v2: C = (A @ Bt^T) + bias. 64x128 tile, 4 waves,
// BK=32, global_load_lds staging (width 16, linear LDS).
// ============================================================
template <bool OB>
__global__ __launch_bounds__(256) void gemm_bf16_nt(
    const unsigned short* __restrict__ A,
    const unsigned short* __restrict__ Bt,
    void* __restrict__ Cv,
    const float* __restrict__ bias,
    int M, int N, int K)
{
    __shared__ short As[64 * 32];    // 4 KB
    __shared__ short Bs[128 * 32];   // 8 KB
    const int m0 = blockIdx.y * 64, n0 = blockIdx.x * 128;
    const int t = threadIdx.x;
    const int wid = t >> 6, lane = t & 63;
    const int wr = wid >> 1, wc = wid & 1;
    const int lr = lane & 15, lk = (lane >> 4) * 8;

    f32x4 acc[2][4] = {};

    const int srow = lane >> 2;          // 0..15
    const int scol = (lane & 3) * 8;     // shorts: 0,8,16,24

    for (int kb = 0; kb < K; kb += 32) {
        __syncthreads();
        {
            const unsigned short* g = &A[(size_t)(m0 + wid * 16 + srow) * K + kb + scol];
            __builtin_amdgcn_global_load_lds((const unsigned*)g,
                (unsigned*)&As[(wid * 16) * 32], 16, 0, 0);
        }
#pragma unroll
        for (int u = 0; u < 2; ++u) {
            const unsigned short* g = &Bt[(size_t)(n0 + wid * 32 + u * 16 + srow) * K + kb + scol];
            __builtin_amdgcn_global_load_lds((const unsigned*)g,
                (unsigned*)&Bs[(wid * 32 + u * 16) * 32], 16, 0, 0);
        }
        __syncthreads();

        s16x8 af[2], bf[4];
#pragma unroll
        for (int i = 0; i < 2; ++i)
            af[i] = *(const s16x8*)&As[(wr * 32 + i * 16 + lr) * 32 + lk];
#pragma unroll
        for (int j = 0; j < 4; ++j)
            bf[j] = *(const s16x8*)&Bs[(wc * 64 + j * 16 + lr) * 32 + lk];
#pragma unroll
        for (int i = 0; i < 2; ++i)
#pragma unroll
            for (int j = 0; j < 4; ++j)
                acc[i][j] = __builtin_amdgcn_mfma_f32_16x16x32_bf16(
                    af[i], bf[j], acc[i][j], 0, 0, 0);
    }

    const int r0 = (lane >> 4) * 4;
#pragma unroll
    for (int i = 0; i < 2; ++i) {
        const int row = m0 + wr * 32 + i * 16 + r0;
#pragma unroll
        for (int j = 0; j < 4; ++j) {
            const int col = n0 + wc * 64 + j * 16 + lr;
            const float bvv = bias ? bias[col] : 0.0f;
#pragma unroll
            for (int r = 0; r < 4; ++r) {
                const float val = acc[i][j][r] + bvv;
                if (OB) ((unsigned short*)Cv)[(size_t)(row + r) * N + col] = f2b1(val);
                else    ((float*)Cv)[(size_t)(row + r) * N + col] = val;
            }
        }
    }
}

// ============================================================
// Fused scores + softmax + 3x da-renorm, v2 hybrid (round-11/12
// proven, 57 us). Reverted from the v3 regression.
// ============================================================
__global__ __launch_bounds__(512) void attn_fused(
    const unsigned short* __restrict__ Qb,
    const unsigned short* __restrict__ Kb,
    const unsigned short* __restrict__ D,
    unsigned short* __restrict__ Ab)
{
    constexpr int KP = 72;    // Q/K staging pitch (shorts)
    constexpr int SP = 520;   // e-tile pitch (shorts)
    __shared__ short pool[64 * SP];   // 66560 B; Qs/Ks alias inside
    __shared__ float red[8][64];
    short* Qs = pool;
    short* Ks = pool + 4608;

    const int z = blockIdx.y;
    const int b = z >> 4, h = z & 15;
    const int q0 = blockIdx.x * 64;
    const int t = threadIdx.x;
    const int wid = t >> 6, lane = t & 63;
    const int lr = lane & 15, lkq = (lane >> 4) * 8;
    const int rbase = (lane >> 4) * 4;

    // ---- Phase A: load Q tile, MFMA scores ----
    {
        const int row = t >> 3, seg = (t & 7) * 8;
        *(uint4*)&Qs[row * KP + seg] =
            *(const uint4*)&Qb[((size_t)(b * LQ + q0 + row)) * DM + h * DK + seg];
    }

    f32x4 acc[2][4][2] = {};   // [kh][i][j]

#pragma unroll
    for (int kh = 0; kh < 2; ++kh) {
        __syncthreads();
        {
            const int row = t >> 1, seg = (t & 1) * 32;
            const unsigned short* src =
                &Kb[((size_t)(b * LK + kh * 256 + row)) * DM + h * DK + seg];
#pragma unroll
            for (int s = 0; s < 4; ++s)
                *(uint4*)&Ks[row * KP + seg + s * 8] = *(const uint4*)(src + s * 8);
        }
        __syncthreads();

#pragma unroll
        for (int ks = 0; ks < 2; ++ks) {
            s16x8 af[4], bf[2];
#pragma unroll
            for (int i = 0; i < 4; ++i)
                af[i] = *(const s16x8*)&Qs[(i * 16 + lr) * KP + ks * 32 + lkq];
#pragma unroll
            for (int j = 0; j < 2; ++j)
                bf[j] = *(const s16x8*)&Ks[(wid * 32 + j * 16 + lr) * KP + ks * 32 + lkq];
#pragma unroll
            for (int i = 0; i < 4; ++i)
#pragma unroll
                for (int j = 0; j < 2; ++j)
                    acc[kh][i][j] = __builtin_amdgcn_mfma_f32_16x16x32_bf16(
                        af[i], bf[j], acc[kh][i][j], 0, 0, 0);
        }
    }

    // ---- row max (only cross-lane reduce in MFMA layout) ----
    float M[4][4];
#pragma unroll
    for (int i = 0; i < 4; ++i)
#pragma unroll
        for (int r = 0; r < 4; ++r) {
            float m = acc[0][i][0][r];
            m = fmaxf(m, acc[0][i][1][r]);
            m = fmaxf(m, acc[1][i][0][r]);
            m = fmaxf(m, acc[1][i][1][r]);
#pragma unroll
            for (int o = 1; o < 16; o <<= 1)
                m = fmaxf(m, __shfl_xor(m, o));
            M[i][r] = m;
        }
    __syncthreads();           // MFMA reads of Qs/Ks complete
    if (lr == 0) {
#pragma unroll
        for (int i = 0; i < 4; ++i)
#pragma unroll
            for (int r = 0; r < 4; ++r)
                red[wid][i * 16 + rbase + r] = M[i][r];
    }
    __syncthreads();
#pragma unroll
    for (int i = 0; i < 4; ++i)
#pragma unroll
        for (int r = 0; r < 4; ++r) {
            float m = red[0][i * 16 + rbase + r];
#pragma unroll
            for (int ww = 1; ww < 8; ++ww)
                m = fmaxf(m, red[ww][i * 16 + rbase + r]);
            M[i][r] = m;
        }

    // ---- Phase B: exp -> bf16 e-tile in LDS (overwrites Qs/Ks) ----
#pragma unroll
    for (int kh = 0; kh < 2; ++kh)
#pragma unroll
        for (int i = 0; i < 4; ++i)
#pragma unroll
            for (int j = 0; j < 2; ++j) {
                const int col = kh * 256 + wid * 32 + j * 16 + lr;
#pragma unroll
                for (int r = 0; r < 4; ++r) {
                    const int row = i * 16 + rbase + r;
                    const float e = __expf((acc[kh][i][j][r] - M[i][r]) * 0.125f);
                    pool[row * SP + col] = (short)f2b1(e);
                }
            }
    __syncthreads();

    // ---- Phase C: row-parallel softmax-z + 3x da-renorm ----
    for (int rr = wid * 8; rr < wid * 8 + 8; ++rr) {
        float v[8];
        {
            const uint4 ev = *(const uint4*)&pool[rr * SP + lane * 8];
            const unsigned short* pe = (const unsigned short*)&ev;
#pragma unroll
            for (int j = 0; j < 8; ++j) v[j] = b2f1(pe[j]);
        }
        float s = 0.0f;
#pragma unroll
        for (int j = 0; j < 8; ++j) s += v[j];
#pragma unroll
        for (int o = 32; o > 0; o >>= 1) s += __shfl_xor(s, o);
        const float invz = 1.0f / s;
#pragma unroll
        for (int j = 0; j < 8; ++j) v[j] *= invz;

#pragma unroll
        for (int it = 0; it < 3; ++it) {
            const uint4 dv = *(const uint4*)&D[
                (((size_t)it * B_ + b) * LQ + q0 + rr) * LK + lane * 8];
            const unsigned short* pd = (const unsigned short*)&dv;
            float s2 = 0.0f;
#pragma unroll
            for (int j = 0; j < 8; ++j) {
                v[j] *= b2f1(pd[j]);
                s2 += v[j];
            }
#pragma unroll
            for (int o = 32; o > 0; o >>= 1) s2 += __shfl_xor(s2, o);
            const float inv = 1.0f / fmaxf(s2, 1e-9f);
#pragma unroll
            for (int j = 0; j < 8; ++j) v[j] *= inv;
        }

        ushort4 u0, u1;
        u0.x = f2b1(v[0]); u0.y = f2b1(v[1]); u0.z = f2b1(v[2]); u0.w = f2b1(v[3]);
        u1.x = f2b1(v[4]); u1.y = f2b1(v[5]); u1.z = f2b1(v[6]); u1.w = f2b1(v[7]);
        unsigned short* arow = Ab + ((size_t)z * LQ + q0 + rr) * LK + lane * 8;
        *(ushort4*)&arow[0] = u0;
        *(ushort4*)&arow[4] = u1;
    }
}

// ============================================================
// meanOut[b][q][k] = (1/16) * sum_h Ab[b*16+h][q][k]
// ============================================================
__global__ __launch_bounds__(256) void meanB_kernel(
    const unsigned short* __restrict__ Ab, float* __restrict__ meanOut)
{
    const int b = blockIdx.x >> 9, q = blockIdx.x & 511;
    const int t = threadIdx.x;
    const int c0 = t * 2;
    float s0 = 0.0f, s1 = 0.0f;
#pragma unroll
    for (int h = 0; h < 16; ++h) {
        const unsigned short* row = Ab + (((size_t)(b * 16 + h)) * LQ + q) * LK;
        const unsigned v = *(const unsigned*)&row[c0];
        s0 += b2f1((unsigned short)(v & 0xffff));
        s1 += b2f1((unsigned short)(v >> 16));
    }
    float* o = meanOut + ((size_t)b * LQ + q) * LK + c0;
    o[0] = s0 * (1.0f / 16.0f);
    o[1] = s1 * (1.0f / 16.0f);
}

// ============================================================
// ctx v2: LDS-free, barrier-free. Both operands are L2/L3-resident
// (Ab just written -> L3; VbT 64KB panel per z -> L2). MFMA frags
// read directly from global; latency hidden by high occupancy.
// z = b*16+h (all 128). 64x64 tile, 4 waves, BK=32 per iter.
// ============================================================
__global__ __launch_bounds__(256) void ctx_mfma(
    const unsigned short* __restrict__ Ab,
    const unsigned short* __restrict__ VbT,
    unsigned short* __restrict__ ctxb)
{
    const int z = blockIdx.z;
    const int b = z >> 4, h = z & 15;
    const int hcol = h * DK;
    const int q0 = blockIdx.y * 64;
    const int t = threadIdx.x;
    const int wid = t >> 6, lane = t & 63;
    const int wr = wid >> 1, wc = wid & 1;
    const int lr = lane & 15, lk = (lane >> 4) * 8;

    const unsigned short* Abase = Ab + ((size_t)z * LQ + q0) * LK;
    const unsigned short* Bbase = VbT + (size_t)hcol * (B_ * LK) + (size_t)b * LK;

    f32x4 acc[2][2] = {};

    for (int kb = 0; kb < LK; kb += 32) {
        s16x8 af[2], bf[2];
#pragma unroll
        for (int i = 0; i < 2; ++i)
            af[i] = *(const s16x8*)&Abase[(size_t)(wr * 32 + i * 16 + lr) * LK + kb + lk];
#pragma unroll
        for (int j = 0; j < 2; ++j)
            bf[j] = *(const s16x8*)&Bbase[(size_t)(wc * 32 + j * 16 + lr) * (B_ * LK) + kb + lk];
#pragma unroll
        for (int i = 0; i < 2; ++i)
#pragma unroll
            for (int j = 0; j < 2; ++j)
                acc[i][j] = __builtin_amdgcn_mfma_f32_16x16x32_bf16(
                    af[i], bf[j], acc[i][j], 0, 0, 0);
    }

    const int r0 = (lane >> 4) * 4;
#pragma unroll
    for (int i = 0; i < 2; ++i) {
        const int row = b * LQ + q0 + wr * 32 + i * 16 + r0;
#pragma unroll
        for (int j = 0; j < 2; ++j) {
            const int col = hcol + wc * 32 + j * 16 + lr;
#pragma unroll
            for (int r = 0; r < 4; ++r)
                ctxb[(size_t)(row + r) * DM + col] = f2b1(acc[i][j][r]);
        }
    }
}

// ============================================================
// fp32 GEMM (fallback path only)
// ============================================================
template <bool BT>
__global__ __launch_bounds__(256) void gemm64(
    const float* __restrict__ A, int lda, long aS1, long aS2,
    const float* __restrict__ Bm, int ldb, long bS1, long bS2,
    float* __restrict__ C, int ldc, long cS1, long cS2,
    const float* __restrict__ bias, int K, float alpha, int zshift)
{
    const int z = blockIdx.z;
    const long z1 = z >> zshift;
    const long z2 = z & ((1 << zshift) - 1);
    A  += z1 * aS1 + z2 * aS2;
    Bm += z1 * bS1 + z2 * bS2;
    C  += z1 * cS1 + z2 * cS2;

    const int m0 = blockIdx.y * 64, n0 = blockIdx.x * 64;
    __shared__ float As[32][68];
    __shared__ float Bs[32][68];
    const int t = threadIdx.x;
    const int ty = t >> 4, tx = t & 15;

    float acc[4][4];
#pragma unroll
    for (int i = 0; i < 4; ++i)
#pragma unroll
        for (int j = 0; j < 4; ++j) acc[i][j] = 0.0f;

    const int mA = t >> 3;
    const int kA = (t & 7) * 4;

    for (int kb = 0; kb < K; kb += 32) {
        {
            const float4 a0 = *(const float4*)&A[(size_t)(m0 + mA) * lda + kb + kA];
            const float4 a1 = *(const float4*)&A[(size_t)(m0 + mA + 32) * lda + kb + kA];
            As[kA + 0][mA] = a0.x; As[kA + 1][mA] = a0.y; As[kA + 2][mA] = a0.z; As[kA + 3][mA] = a0.w;
            As[kA + 0][mA + 32] = a1.x; As[kA + 1][mA + 32] = a1.y; As[kA + 2][mA + 32] = a1.z; As[kA + 3][mA + 32] = a1.w;
        }
        if (BT) {
            const float4 b0 = *(const float4*)&Bm[(size_t)(n0 + mA) * ldb + kb + kA];
            const float4 b1 = *(const float4*)&Bm[(size_t)(n0 + mA + 32) * ldb + kb + kA];
            Bs[kA + 0][mA] = b0.x; Bs[kA + 1][mA] = b0.y; Bs[kA + 2][mA] = b0.z; Bs[kA + 3][mA] = b0.w;
            Bs[kA + 0][mA + 32] = b1.x; Bs[kA + 1][mA + 32] = b1.y; Bs[kA + 2][mA + 32] = b1.z; Bs[kA + 3][mA + 32] = b1.w;
        } else {
            const int kB = t >> 4;
            const int nB = (t & 15) * 4;
            const float4 b0 = *(const float4*)&Bm[(size_t)(kb + kB) * ldb + n0 + nB];
            const float4 b1 = *(const float4*)&Bm[(size_t)(kb + kB + 16) * ldb + n0 + nB];
            *(float4*)&Bs[kB][nB] = b0;
            *(float4*)&Bs[kB + 16][nB] = b1;
        }
        __syncthreads();

#pragma unroll
        for (int kk = 0; kk < 32; ++kk) {
            const float4 av = *(const float4*)&As[kk][ty * 4];
            const float4 bv = *(const float4*)&Bs[kk][tx * 4];
            const float a[4] = {av.x, av.y, av.z, av.w};
            const float bb[4] = {bv.x, bv.y, bv.z, bv.w};
#pragma unroll
            for (int i = 0; i < 4; ++i)
#pragma unroll
                for (int j = 0; j < 4; ++j)
                    acc[i][j] = fmaf(a[i], bb[j], acc[i][j]);
        }
        __syncthreads();
    }

#pragma unroll
    for (int i = 0; i < 4; ++i) {
        const int row = m0 + ty * 4 + i;
        float4 o;
        o.x = acc[i][0] * alpha;
        o.y = acc[i][1] * alpha;
        o.z = acc[i][2] * alpha;
        o.w = acc[i][3] * alpha;
        if (bias) {
            o.x += bias[n0 + tx * 4 + 0];
            o.y += bias[n0 + tx * 4 + 1];
            o.z += bias[n0 + tx * 4 + 2];
            o.w += bias[n0 + tx * 4 + 3];
        }
        *(float4*)&C[(size_t)row * ldc + n0 + tx * 4] = o;
    }
}

// ============================================================
// softmax + 3x renorm (fallback path only; fp32 in-place)
// ============================================================
template <bool BF16OUT>
__global__ __launch_bounds__(256) void softmaxP_kernel(
    float* __restrict__ S, const unsigned short* __restrict__ D,
    void* __restrict__ AOut, float* __restrict__ meanOut,
    int nheads, int accumulate)
{
    const int b = blockIdx.x >> 9, q = blockIdx.x & 511;
    const int t = threadIdx.x, w = t >> 6, lane = t & 63;
    __shared__ float Pl[3][LK];
    __shared__ float part[4][LK];
    const size_t NPB = (size_t)B_ * LQ * LK;
    const size_t rowoff = ((size_t)b * LQ + q) * LK;

    for (int i = t; i < LK; i += 256) {
        Pl[0][i] = b2f1(D[rowoff + i]);
        Pl[1][i] = b2f1(D[NPB + rowoff + i]);
        Pl[2][i] = b2f1(D[2 * NPB + rowoff + i]);
    }
    __syncthreads();

    float macc[8];
#pragma unroll
    for (int j = 0; j < 8; ++j) macc[j] = 0.0f;

    for (int h = w; h < nheads; h += 4) {
        const size_t roff = (((size_t)b * nheads + h) * LQ + q) * LK;
        const float* row = S + roff;
        float v[8];
        const float4 s0 = *(const float4*)&row[lane * 8];
        const float4 s1 = *(const float4*)&row[lane * 8 + 4];
        v[0] = s0.x; v[1] = s0.y; v[2] = s0.z; v[3] = s0.w;
        v[4] = s1.x; v[5] = s1.y; v[6] = s1.z; v[7] = s1.w;
        float mx = v[0];
#pragma unroll
        for (int j = 1; j < 8; ++j) mx = fmaxf(mx, v[j]);
#pragma unroll
        for (int o = 32; o > 0; o >>= 1) mx = fmaxf(mx, __shfl_xor(mx, o));
        float zz = 0.0f;
#pragma unroll
        for (int j = 0; j < 8; ++j) { v[j] = __expf(v[j] - mx); zz += v[j]; }
#pragma unroll
        for (int o = 32; o > 0; o >>= 1) zz += __shfl_xor(zz, o);
        const float invz = 1.0f / zz;
#pragma unroll
        for (int j = 0; j < 8; ++j) v[j] *= invz;

#pragma unroll
        for (int it = 0; it < 3; ++it) {
            float s = 0.0f;
#pragma unroll
            for (int j = 0; j < 8; ++j) {
                v[j] *= Pl[it][lane * 8 + j];
                s += v[j];
            }
#pragma unroll
            for (int o = 32; o > 0; o >>= 1) s += __shfl_xor(s, o);
            const float inv = 1.0f / fmaxf(s, 1e-9f);
#pragma unroll
            for (int j = 0; j < 8; ++j) v[j] *= inv;
        }

#pragma unroll
        for (int j = 0; j < 8; ++j) macc[j] += v[j];

        if (BF16OUT) {
            unsigned short* arow = (unsigned short*)AOut + roff;
            ushort4 u0, u1;
            u0.x = f2b1(v[0]); u0.y = f2b1(v[1]); u0.z = f2b1(v[2]); u0.w = f2b1(v[3]);
            u1.x = f2b1(v[4]); u1.y = f2b1(v[5]); u1.z = f2b1(v[6]); u1.w = f2b1(v[7]);
            *(ushort4*)&arow[lane * 8] = u0;
            *(ushort4*)&arow[lane * 8 + 4] = u1;
        } else {
            float* arow = (float*)AOut + roff;
            *(float4*)&arow[lane * 8] = make_float4(v[0], v[1], v[2], v[3]);
            *(float4*)&arow[lane * 8 + 4] = make_float4(v[4], v[5], v[6], v[7]);
        }
    }

    *(float4*)&part[w][lane * 8] = make_float4(macc[0], macc[1], macc[2], macc[3]);
    *(float4*)&part[w][lane * 8 + 4] = make_float4(macc[4], macc[5], macc[6], macc[7]);
    __syncthreads();

    for (int i = t; i < LK; i += 256) {
        const float m = (part[0][i] + part[1][i] + part[2][i] + part[3][i]) * (1.0f / 16.0f);
        const size_t oi = ((size_t)b * LQ + q) * LK + i;
        meanOut[oi] = accumulate ? (meanOut[oi] + m) : m;
    }
}

// ============================================================
// Launcher
// ============================================================
extern "C" void kernel_launch(void* const* d_in, const int* in_sizes, int n_in,
                              void* d_out, int out_size, void* d_ws, size_t ws_size,
                              hipStream_t stream)
{
    const float* query  = (const float*)d_in[0];
    const float* key    = (const float*)d_in[1];
    const float* value  = (const float*)d_in[2];
    const int*   qlen   = (const int*)d_in[3];
    const int*   klen   = (const int*)d_in[4];
    const float* Wq     = (const float*)d_in[5];
    const float* bq     = (const float*)d_in[6];
    const float* Wk     = (const float*)d_in[7];
    const float* bk     = (const float*)d_in[8];
    const float* Wv     = (const float*)d_in[9];
    const float* bv     = (const float*)d_in[10];
    const float* Wo     = (const float*)d_in[11];
    const float* bo     = (const float*)d_in[12];
    const float* pscale = (const float*)d_in[13];
    const float* pbias  = (const float*)d_in[14];

    float* out     = (float*)d_out;
    float* meanOut = out + (size_t)B_ * LQ * DM;

    const size_t NQKV = (size_t)B_ * LQ * DM;      // 4,194,304
    const size_t NP   = (size_t)B_ * LQ * LK;      // 2,097,152
    const size_t NW   = (size_t)DM * DM;           // 1,048,576
    const size_t NS   = (size_t)B_ * NH * LQ * LK; // 33,554,432
    const size_t NPOS = (size_t)B_ * LQ;           // 4096
    const size_t NCOL = (size_t)B_ * 16 * LK;      // 65536

    // ---------- full-path layout ----------
    unsigned short* Dbuf = (unsigned short*)d_ws;  // 3*NP bf16
    float* posQ  = (float*)(Dbuf + 3 * NP);
    float* posK1 = posQ + NPOS;
    float* posK2 = posK1 + NPOS;
    float* rs1   = posK2 + NPOS;
    float* rd1   = rs1 + NPOS;
    float* rs2   = rd1 + NPOS;
    float* rd2   = rs2 + NPOS;
    float* colS1 = rd2 + NPOS;
    float* colD1 = colS1 + NCOL;
    float* colS2 = colD1 + NCOL;
    float* colD2 = colS2 + NCOL;
    float* fend  = colD2 + NCOL;
    unsigned short* Qb   = (unsigned short*)fend;
    unsigned short* Kb   = Qb + NQKV;
    unsigned short* Vb   = Kb + NQKV;
    unsigned short* VbT  = Vb + NQKV;
    unsigned short* ctxb = VbT + NQKV;
    unsigned short* wqb  = ctxb + NQKV;
    unsigned short* wkb  = wqb + NW;
    unsigned short* wvb  = wkb + NW;
    unsigned short* wob  = wvb + NW;
    unsigned short* Ab   = wob + NW;               // NS shorts (67 MB)
    // f2b staging aliased into Ab (dead until attn_fused)
    unsigned short* xq = Ab;
    unsigned short* xk = xq + NQKV;
    unsigned short* xv = xk + NQKV;

    const size_t need_full = (size_t)((char*)(Ab + NS) - (char*)d_ws);

    if (ws_size >= need_full) {
        // positions + da tensors: 3 launches
        dim3 gDa(16, B_);
        daRow_kernel<0><<<gDa, 512, 0, stream>>>(qlen, klen, pscale, pbias,
            posQ, nullptr, posK1,
            nullptr, nullptr, nullptr, nullptr,
            rs1, rd1, colS1, colD1, Dbuf);
        daRow_kernel<1><<<gDa, 512, 0, stream>>>(qlen, klen, pscale, pbias,
            posQ, posK1, posK2,
            rs1, rd1, colS1, colD1,
            rs2, rd2, colS2, colD2, Dbuf + NP);
        daRow_kernel<2><<<gDa, 512, 0, stream>>>(qlen, klen, pscale, pbias,
            posQ, posK2, nullptr,
            rs2, rd2, colS2, colD2,
            nullptr, nullptr, nullptr, nullptr, Dbuf + 2 * NP);

        // all bf16 conversions: 1 launch
        dim3 gF(1024, 16);
        f2b_all_kernel<<<gF, 256, 0, stream>>>(query, key, value, Wq, Wk, Wv, Wo,
                                               xq, xk, xv, wqb, wkb, wvb, wob);

        // Q/K/V projections: 3 separate 64x128 launches (gload_lds v2)
        dim3 gP(DM / 128, (B_ * LQ) / 64);
        gemm_bf16_nt<true><<<gP, 256, 0, stream>>>(xq, wqb, Qb, bq, B_ * LQ, DM, DM);
        gemm_bf16_nt<true><<<gP, 256, 0, stream>>>(xk, wkb, Kb, bk, B_ * LQ, DM, DM);
        gemm_bf16_nt<true><<<gP, 256, 0, stream>>>(xv, wvb, Vb, bv, B_ * LQ, DM, DM);

        // V transpose: [4096][1024] -> [1024][4096]
        dim3 gT(DM / 64, (B_ * LK) / 64);
        transpose_bf16<<<gT, 256, 0, stream>>>(Vb, VbT, B_ * LK, DM);

        // fused scores+softmax+renorm -> bf16 attn (all 16 heads)
        dim3 gA(LQ / 64, B_ * NH);
        attn_fused<<<gA, 512, 0, stream>>>(Qb, Kb, Dbuf, Ab);

        // meanOut from bf16 attn
        meanB_kernel<<<B_ * LQ, 256, 0, stream>>>(Ab, meanOut);

        // ctx for all heads (LDS-free v2)
        dim3 gC(1, LQ / 64, B_ * NH);
        ctx_mfma<<<gC, 256, 0, stream>>>(Ab, VbT, ctxb);

        // out = ctx @ Wo^T + bo (fp32 out)
        gemm_bf16_nt<false><<<gP, 256, 0, stream>>>(ctxb, wob, out, bo, B_ * LQ, DM, DM);
        return;
    }

    // ---------- fp32 fallback (chunked per-head) ----------
    float* qbuf = (float*)d_ws;
    float* kbuf = qbuf + NQKV;
    float* vbuf = kbuf + NQKV;
    unsigned short* Dfb = (unsigned short*)(vbuf + NQKV);  // 3*NP bf16
    float* Sfb  = (float*)(Dfb + 3 * NP);        // NP
    float* ctxbuf = Sfb + NP;                    // NQKV
    float* pQ  = ctxbuf + NQKV;
    float* pK1 = pQ + NPOS;
    float* pK2 = pK1 + NPOS;
    float* frs1 = pK2 + NPOS;
    float* frd1 = frs1 + NPOS;
    float* frs2 = frd1 + NPOS;
    float* frd2 = frs2 + NPOS;
    float* fcS1 = frd2 + NPOS;
    float* fcD1 = fcS1 + NCOL;
    float* fcS2 = fcD1 + NCOL;
    float* fcD2 = fcS2 + NCOL;

    dim3 gDa(16, B_);
    daRow_kernel<0><<<gDa, 512, 0, stream>>>(qlen, klen, pscale, pbias,
        pQ, nullptr, pK1, nullptr, nullptr, nullptr, nullptr,
        frs1, frd1, fcS1, fcD1, Dfb);
    daRow_kernel<1><<<gDa, 512, 0, stream>>>(qlen, klen, pscale, pbias,
        pQ, pK1, pK2, frs1, frd1, fcS1, fcD1,
        frs2, frd2, fcS2, fcD2, Dfb + NP);
    daRow_kernel<2><<<gDa, 512, 0, stream>>>(qlen, klen, pscale, pbias,
        pQ, pK2, nullptr, frs2, frd2, fcS2, fcD2,
        nullptr, nullptr, nullptr, nullptr, Dfb + 2 * NP);

    dim3 gProj(DM / 64, (B_ * LQ) / 64, 1);
    gemm64<true><<<gProj, 256, 0, stream>>>(query, DM, 0, 0, Wq, DM, 0, 0,
                                            qbuf, DM, 0, 0, bq, DM, 1.0f, 0);
    gemm64<true><<<gProj, 256, 0, stream>>>(key, DM, 0, 0, Wk, DM, 0, 0,
                                            kbuf, DM, 0, 0, bk, DM, 1.0f, 0);
    gemm64<true><<<gProj, 256, 0, stream>>>(value, DM, 0, 0, Wv, DM, 0, 0,
                                            vbuf, DM, 0, 0, bv, DM, 1.0f, 0);
    for (int h = 0; h < NH; ++h) {
        dim3 gS2(LK / 64, LQ / 64, B_);
        gemm64<true><<<gS2, 256, 0, stream>>>(
            qbuf + h * DK, DM, (long)LQ * DM, 0,
            kbuf + h * DK, DM, (long)LK * DM, 0,
            Sfb, LK, (long)LQ * LK, 0,
            nullptr, DK, 0.125f, 0);
        softmaxP_kernel<false><<<B_ * LQ, 256, 0, stream>>>(Sfb, Dfb, Sfb, meanOut, 1, h > 0 ? 1 : 0);
        dim3 gC2(1, LQ / 64, B_);
        gemm64<false><<<gC2, 256, 0, stream>>>(
            Sfb, LK, (long)LQ * LK, 0,
            vbuf + h * DK, DM, (long)LK * DM, 0,
            ctxbuf + h * DK, DM, (long)LQ * DM, 0,
            nullptr, LK, 1.0f, 0);
    }
    dim3 gO(DM / 64, (B_ * LQ) / 64, 1);
    gemm64<true><<<gO, 256, 0, stream>>>(ctxbuf, DM, 0, 0, Wo, DM, 0, 0,
                                         out, DM, 0, 0, bo, DM, 1.0f, 0);
}

// Round 15
// 213.259 us; speedup vs baseline: 1.0695x; 1.0695x over previous
//
#include <hip/hip_runtime.h>
#include <math.h>

#define B_  8
#define LQ  512
#define LK  512
#define DM  1024
#define NH  16
#define DK  64
constexpr float PADP = 10000.0f;

typedef short s16x8 __attribute__((ext_vector_type(8)));
typedef float f32x4 __attribute__((ext_vector_type(4)));

// ============================================================
// fp32 <-> bf16 helpers
// ============================================================
__device__ inline unsigned short f2b1(float f) {
    unsigned u = __float_as_uint(f);
    unsigned r = (u + 0x7fffu + ((u >> 16) & 1u)) >> 16;
    return (unsigned short)r;
}
__device__ inline float b2f1(unsigned short h) {
    return __uint_as_float(((unsigned)h) << 16);
}

// One launch converts q,k,v (4 slots of 1M elems each) + 4 weights.
__global__ __launch_bounds__(256) void f2b_all_kernel(
    const float* __restrict__ query, const float* __restrict__ key,
    const float* __restrict__ value,
    const float* __restrict__ Wq, const float* __restrict__ Wk,
    const float* __restrict__ Wv, const float* __restrict__ Wo,
    unsigned short* __restrict__ xq, unsigned short* __restrict__ xk,
    unsigned short* __restrict__ xv,
    unsigned short* __restrict__ wqb, unsigned short* __restrict__ wkb,
    unsigned short* __restrict__ wvb, unsigned short* __restrict__ wob)
{
    const int s = blockIdx.y;
    const float* src;
    unsigned short* dst;
    if (s < 4)       { src = query + ((size_t)s << 20);       dst = xq + ((size_t)s << 20); }
    else if (s < 8)  { src = key   + ((size_t)(s - 4) << 20); dst = xk + ((size_t)(s - 4) << 20); }
    else if (s < 12) { src = value + ((size_t)(s - 8) << 20); dst = xv + ((size_t)(s - 8) << 20); }
    else {
        const int w = s - 12;
        src = (w == 0) ? Wq : (w == 1) ? Wk : (w == 2) ? Wv : Wo;
        dst = (w == 0) ? wqb : (w == 1) ? wkb : (w == 2) ? wvb : wob;
    }
    const int i = blockIdx.x * 256 + threadIdx.x;
    const float4 v = *(const float4*)&src[(size_t)i * 4];
    ushort4 o;
    o.x = f2b1(v.x); o.y = f2b1(v.y); o.z = f2b1(v.z); o.w = f2b1(v.w);
    *(ushort4*)&dst[(size_t)i * 4] = o;
}

// ============================================================
// Position pipeline: 3 launches of daRow<PHASE>. D planes bf16.
// ============================================================
template <int PHASE>
__global__ __launch_bounds__(512) void daRow_kernel(
    const int* __restrict__ qlen, const int* __restrict__ klen,
    const float* __restrict__ pscale, const float* __restrict__ pbias,
    float* __restrict__ posQ,
    const float* __restrict__ posKin, float* __restrict__ posKout,
    const float* __restrict__ rsIn, const float* __restrict__ rdIn,
    const float* __restrict__ colSIn, const float* __restrict__ colDIn,
    float* __restrict__ rsOut, float* __restrict__ rdOut,
    float* __restrict__ colSOut, float* __restrict__ colDOut,
    unsigned short* __restrict__ Dplane)
{
    constexpr int NCH = 16, QC = LQ / NCH;
    __shared__ float kpl[LK];
    __shared__ float csp[8][LK], cdp[8][LK];
    const int chunk = blockIdx.x, b = blockIdx.y;
    const int t = threadIdx.x, w = t >> 6, lane = t & 63;

    float scale = 0.0f, bias = 0.0f;
    if (PHASE == 0) { scale = pscale[0]; bias = pbias[0]; }

    if (PHASE == 0) {
        const int kl = klen[b];
        const float Lf = (float)kl;
        const float step = (Lf > 1.0f) ? Lf / (Lf - 1.0f) : 0.0f;
        const float pos = (-Lf * 0.5f + (float)t * step) * scale + bias;
        const float kv = (t >= kl) ? PADP : pos;
        kpl[t] = kv;
        if (chunk == 0) posKout[b * LK + t] = kv;
    } else {
        float colsum = 0.0f, coldot = 0.0f;
#pragma unroll
        for (int c = 0; c < NCH; ++c) {
            colsum += colSIn[((size_t)b * NCH + c) * LK + t];
            coldot += colDIn[((size_t)b * NCH + c) * LK + t];
        }
        const float prev = posKin[b * LK + t];
        const float kv = (prev >= 1000.0f) ? PADP : coldot / fmaxf(colsum, 1e-9f);
        kpl[t] = kv;
        if (PHASE == 1 && chunk == 0) posKout[b * LK + t] = kv;
    }
    __syncthreads();

    float cs[8] = {0,0,0,0,0,0,0,0}, cd[8] = {0,0,0,0,0,0,0,0};
    unsigned short* Dbb = Dplane + (size_t)b * LQ * LK;

    for (int qi = chunk * QC + w; qi < chunk * QC + QC; qi += 8) {
        float qpv;
        if (PHASE == 0) {
            const int ql = qlen[b];
            const float Lf = (float)ql;
            const float step = (Lf > 1.0f) ? Lf / (Lf - 1.0f) : 0.0f;
            qpv = (qi >= ql) ? PADP : (-Lf * 0.5f + (float)qi * step) * scale + bias;
            if (lane == 0) posQ[b * LQ + qi] = qpv;
        } else {
            const float prev = posQ[b * LQ + qi];
            qpv = (prev >= 1000.0f) ? PADP
                : rdIn[b * LQ + qi] / fmaxf(rsIn[b * LQ + qi], 1e-9f);
            if (PHASE == 1 && lane == 0) posQ[b * LQ + qi] = qpv;
        }
        const bool qpad = (qpv >= 1000.0f);
        float rsum = 0.0f, rdot = 0.0f;
#pragma unroll
        for (int c = 0; c < 8; ++c) {
            const int k = lane + 64 * c;
            const float kpv = kpl[k];
            const float d = qpv - kpv;
            float e = (qpad || (kpv >= 1000.0f)) ? 0.0f : __expf(-0.5f * d * d);
            if (PHASE < 2) { rsum += e; rdot += e * kpv; cs[c] += e; cd[c] += e * qpv; }
            Dbb[(size_t)qi * LK + k] = f2b1(e);
        }
        if (PHASE < 2) {
#pragma unroll
            for (int o = 32; o > 0; o >>= 1) {
                rsum += __shfl_xor(rsum, o);
                rdot += __shfl_xor(rdot, o);
            }
            if (lane == 0) { rsOut[b * LQ + qi] = rsum; rdOut[b * LQ + qi] = rdot; }
        }
    }
    if (PHASE < 2) {
#pragma unroll
        for (int c = 0; c < 8; ++c) {
            csp[w][lane + 64 * c] = cs[c];
            cdp[w][lane + 64 * c] = cd[c];
        }
        __syncthreads();
        float s = 0.0f, dd = 0.0f;
        for (int ww = 0; ww < 8; ++ww) { s += csp[ww][t]; dd += cdp[ww][t]; }
        colSOut[((size_t)b * NCH + chunk) * LK + t] = s;
        colDOut[((size_t)b * NCH + chunk) * LK + t] = dd;
    }
}

// ============================================================
// bf16 MFMA GEMM v2: C = (A @ Bt^T) + bias. 64x128 tile, 4 waves,
// BK=32, global_load_lds staging (width 16, linear LDS).
// OB: bf16 output. OT: write transposed C[col*M+row] (bf16 only;
// used to produce VbT directly from the V projection).
// ============================================================
template <bool OB, bool OT>
__global__ __launch_bounds__(256) void gemm_bf16_nt(
    const unsigned short* __restrict__ A,
    const unsigned short* __restrict__ Bt,
    void* __restrict__ Cv,
    const float* __restrict__ bias,
    int M, int N, int K)
{
    __shared__ short As[64 * 32];    // 4 KB
    __shared__ short Bs[128 * 32];   // 8 KB
    const int m0 = blockIdx.y * 64, n0 = blockIdx.x * 128;
    const int t = threadIdx.x;
    const int wid = t >> 6, lane = t & 63;
    const int wr = wid >> 1, wc = wid & 1;
    const int lr = lane & 15, lk = (lane >> 4) * 8;

    f32x4 acc[2][4] = {};

    const int srow = lane >> 2;          // 0..15
    const int scol = (lane & 3) * 8;     // shorts: 0,8,16,24

    for (int kb = 0; kb < K; kb += 32) {
        __syncthreads();
        {
            const unsigned short* g = &A[(size_t)(m0 + wid * 16 + srow) * K + kb + scol];
            __builtin_amdgcn_global_load_lds((const unsigned*)g,
                (unsigned*)&As[(wid * 16) * 32], 16, 0, 0);
        }
#pragma unroll
        for (int u = 0; u < 2; ++u) {
            const unsigned short* g = &Bt[(size_t)(n0 + wid * 32 + u * 16 + srow) * K + kb + scol];
            __builtin_amdgcn_global_load_lds((const unsigned*)g,
                (unsigned*)&Bs[(wid * 32 + u * 16) * 32], 16, 0, 0);
        }
        __syncthreads();

        s16x8 af[2], bf[4];
#pragma unroll
        for (int i = 0; i < 2; ++i)
            af[i] = *(const s16x8*)&As[(wr * 32 + i * 16 + lr) * 32 + lk];
#pragma unroll
        for (int j = 0; j < 4; ++j)
            bf[j] = *(const s16x8*)&Bs[(wc * 64 + j * 16 + lr) * 32 + lk];
#pragma unroll
        for (int i = 0; i < 2; ++i)
#pragma unroll
            for (int j = 0; j < 4; ++j)
                acc[i][j] = __builtin_amdgcn_mfma_f32_16x16x32_bf16(
                    af[i], bf[j], acc[i][j], 0, 0, 0);
    }

    const int r0 = (lane >> 4) * 4;
#pragma unroll
    for (int i = 0; i < 2; ++i) {
        const int row = m0 + wr * 32 + i * 16 + r0;
#pragma unroll
        for (int j = 0; j < 4; ++j) {
            const int col = n0 + wc * 64 + j * 16 + lr;
            const float bvv = bias ? bias[col] : 0.0f;
#pragma unroll
            for (int r = 0; r < 4; ++r) {
                const float val = acc[i][j][r] + bvv;
                if (OT)      ((unsigned short*)Cv)[(size_t)col * M + row + r] = f2b1(val);
                else if (OB) ((unsigned short*)Cv)[(size_t)(row + r) * N + col] = f2b1(val);
                else         ((float*)Cv)[(size_t)(row + r) * N + col] = val;
            }
        }
    }
}

// ============================================================
// Fused scores + softmax + 3x da-renorm, v2 hybrid (proven 57 us).
// ============================================================
__global__ __launch_bounds__(512) void attn_fused(
    const unsigned short* __restrict__ Qb,
    const unsigned short* __restrict__ Kb,
    const unsigned short* __restrict__ D,
    unsigned short* __restrict__ Ab)
{
    constexpr int KP = 72;    // Q/K staging pitch (shorts)
    constexpr int SP = 520;   // e-tile pitch (shorts)
    __shared__ short pool[64 * SP];   // 66560 B; Qs/Ks alias inside
    __shared__ float red[8][64];
    short* Qs = pool;
    short* Ks = pool + 4608;

    const int z = blockIdx.y;
    const int b = z >> 4, h = z & 15;
    const int q0 = blockIdx.x * 64;
    const int t = threadIdx.x;
    const int wid = t >> 6, lane = t & 63;
    const int lr = lane & 15, lkq = (lane >> 4) * 8;
    const int rbase = (lane >> 4) * 4;

    // ---- Phase A: load Q tile, MFMA scores ----
    {
        const int row = t >> 3, seg = (t & 7) * 8;
        *(uint4*)&Qs[row * KP + seg] =
            *(const uint4*)&Qb[((size_t)(b * LQ + q0 + row)) * DM + h * DK + seg];
    }

    f32x4 acc[2][4][2] = {};   // [kh][i][j]

#pragma unroll
    for (int kh = 0; kh < 2; ++kh) {
        __syncthreads();
        {
            const int row = t >> 1, seg = (t & 1) * 32;
            const unsigned short* src =
                &Kb[((size_t)(b * LK + kh * 256 + row)) * DM + h * DK + seg];
#pragma unroll
            for (int s = 0; s < 4; ++s)
                *(uint4*)&Ks[row * KP + seg + s * 8] = *(const uint4*)(src + s * 8);
        }
        __syncthreads();

#pragma unroll
        for (int ks = 0; ks < 2; ++ks) {
            s16x8 af[4], bf[2];
#pragma unroll
            for (int i = 0; i < 4; ++i)
                af[i] = *(const s16x8*)&Qs[(i * 16 + lr) * KP + ks * 32 + lkq];
#pragma unroll
            for (int j = 0; j < 2; ++j)
                bf[j] = *(const s16x8*)&Ks[(wid * 32 + j * 16 + lr) * KP + ks * 32 + lkq];
#pragma unroll
            for (int i = 0; i < 4; ++i)
#pragma unroll
                for (int j = 0; j < 2; ++j)
                    acc[kh][i][j] = __builtin_amdgcn_mfma_f32_16x16x32_bf16(
                        af[i], bf[j], acc[kh][i][j], 0, 0, 0);
        }
    }

    // ---- row max (only cross-lane reduce in MFMA layout) ----
    float M[4][4];
#pragma unroll
    for (int i = 0; i < 4; ++i)
#pragma unroll
        for (int r = 0; r < 4; ++r) {
            float m = acc[0][i][0][r];
            m = fmaxf(m, acc[0][i][1][r]);
            m = fmaxf(m, acc[1][i][0][r]);
            m = fmaxf(m, acc[1][i][1][r]);
#pragma unroll
            for (int o = 1; o < 16; o <<= 1)
                m = fmaxf(m, __shfl_xor(m, o));
            M[i][r] = m;
        }
    __syncthreads();           // MFMA reads of Qs/Ks complete
    if (lr == 0) {
#pragma unroll
        for (int i = 0; i < 4; ++i)
#pragma unroll
            for (int r = 0; r < 4; ++r)
                red[wid][i * 16 + rbase + r] = M[i][r];
    }
    __syncthreads();
#pragma unroll
    for (int i = 0; i < 4; ++i)
#pragma unroll
        for (int r = 0; r < 4; ++r) {
            float m = red[0][i * 16 + rbase + r];
#pragma unroll
            for (int ww = 1; ww < 8; ++ww)
                m = fmaxf(m, red[ww][i * 16 + rbase + r]);
            M[i][r] = m;
        }

    // ---- Phase B: exp -> bf16 e-tile in LDS (overwrites Qs/Ks) ----
#pragma unroll
    for (int kh = 0; kh < 2; ++kh)
#pragma unroll
        for (int i = 0; i < 4; ++i)
#pragma unroll
            for (int j = 0; j < 2; ++j) {
                const int col = kh * 256 + wid * 32 + j * 16 + lr;
#pragma unroll
                for (int r = 0; r < 4; ++r) {
                    const int row = i * 16 + rbase + r;
                    const float e = __expf((acc[kh][i][j][r] - M[i][r]) * 0.125f);
                    pool[row * SP + col] = (short)f2b1(e);
                }
            }
    __syncthreads();

    // ---- Phase C: row-parallel softmax-z + 3x da-renorm ----
    for (int rr = wid * 8; rr < wid * 8 + 8; ++rr) {
        float v[8];
        {
            const uint4 ev = *(const uint4*)&pool[rr * SP + lane * 8];
            const unsigned short* pe = (const unsigned short*)&ev;
#pragma unroll
            for (int j = 0; j < 8; ++j) v[j] = b2f1(pe[j]);
        }
        float s = 0.0f;
#pragma unroll
        for (int j = 0; j < 8; ++j) s += v[j];
#pragma unroll
        for (int o = 32; o > 0; o >>= 1) s += __shfl_xor(s, o);
        const float invz = 1.0f / s;
#pragma unroll
        for (int j = 0; j < 8; ++j) v[j] *= invz;

#pragma unroll
        for (int it = 0; it < 3; ++it) {
            const uint4 dv = *(const uint4*)&D[
                (((size_t)it * B_ + b) * LQ + q0 + rr) * LK + lane * 8];
            const unsigned short* pd = (const unsigned short*)&dv;
            float s2 = 0.0f;
#pragma unroll
            for (int j = 0; j < 8; ++j) {
                v[j] *= b2f1(pd[j]);
                s2 += v[j];
            }
#pragma unroll
            for (int o = 32; o > 0; o >>= 1) s2 += __shfl_xor(s2, o);
            const float inv = 1.0f / fmaxf(s2, 1e-9f);
#pragma unroll
            for (int j = 0; j < 8; ++j) v[j] *= inv;
        }

        ushort4 u0, u1;
        u0.x = f2b1(v[0]); u0.y = f2b1(v[1]); u0.z = f2b1(v[2]); u0.w = f2b1(v[3]);
        u1.x = f2b1(v[4]); u1.y = f2b1(v[5]); u1.z = f2b1(v[6]); u1.w = f2b1(v[7]);
        unsigned short* arow = Ab + ((size_t)z * LQ + q0 + rr) * LK + lane * 8;
        *(ushort4*)&arow[0] = u0;
        *(ushort4*)&arow[4] = u1;
    }
}

// ============================================================
// meanOut[b][q][k] = (1/16) * sum_h Ab[b*16+h][q][k]
// ============================================================
__global__ __launch_bounds__(256) void meanB_kernel(
    const unsigned short* __restrict__ Ab, float* __restrict__ meanOut)
{
    const int b = blockIdx.x >> 9, q = blockIdx.x & 511;
    const int t = threadIdx.x;
    const int c0 = t * 2;
    float s0 = 0.0f, s1 = 0.0f;
#pragma unroll
    for (int h = 0; h < 16; ++h) {
        const unsigned short* row = Ab + (((size_t)(b * 16 + h)) * LQ + q) * LK;
        const unsigned v = *(const unsigned*)&row[c0];
        s0 += b2f1((unsigned short)(v & 0xffff));
        s1 += b2f1((unsigned short)(v >> 16));
    }
    float* o = meanOut + ((size_t)b * LQ + q) * LK + c0;
    o[0] = s0 * (1.0f / 16.0f);
    o[1] = s1 * (1.0f / 16.0f);
}

// ============================================================
// ctx (round-12 proven LDS version): ctxb[b,q,h*64+d] =
// bf16( sum_k Ab[z,q,k] * V[b,k,h*64+d] ), z = b*16+h.
// 64x64 tile, 4 waves, BK=64.
// ============================================================
__global__ __launch_bounds__(256) void ctx_mfma(
    const unsigned short* __restrict__ Ab,
    const unsigned short* __restrict__ VbT,
    unsigned short* __restrict__ ctxb)
{
    constexpr int BKP = 72;
    __shared__ short As[64 * BKP];
    __shared__ short Bs[64 * BKP];
    const int z = blockIdx.z;
    const int b = z >> 4, h = z & 15;
    const int hcol = h * DK;
    const int q0 = blockIdx.y * 64;
    const int t = threadIdx.x;
    const int wid = t >> 6, lane = t & 63;
    const int wr = wid >> 1, wc = wid & 1;
    const int lr = lane & 15, lk = (lane >> 4) * 8;

    const unsigned short* Abase = Ab + ((size_t)z * LQ + q0) * LK;
    const unsigned short* Bbase = VbT + (size_t)hcol * (B_ * LK) + (size_t)b * LK;

    f32x4 acc[2][2] = {};
    const int srow = t >> 2, sseg = (t & 3) * 16;

    for (int kb = 0; kb < LK; kb += 64) {
        const uint4 a0 = *(const uint4*)&Abase[(size_t)srow * LK + kb + sseg];
        const uint4 a1 = *(const uint4*)&Abase[(size_t)srow * LK + kb + sseg + 8];
        const uint4 b0 = *(const uint4*)&Bbase[(size_t)srow * (B_ * LK) + kb + sseg];
        const uint4 b1 = *(const uint4*)&Bbase[(size_t)srow * (B_ * LK) + kb + sseg + 8];
        __syncthreads();
        *(uint4*)&As[srow * BKP + sseg] = a0;
        *(uint4*)&As[srow * BKP + sseg + 8] = a1;
        *(uint4*)&Bs[srow * BKP + sseg] = b0;
        *(uint4*)&Bs[srow * BKP + sseg + 8] = b1;
        __syncthreads();

#pragma unroll
        for (int kh = 0; kh < 2; ++kh) {
            s16x8 af[2], bf[2];
#pragma unroll
            for (int i = 0; i < 2; ++i)
                af[i] = *(const s16x8*)&As[(wr * 32 + i * 16 + lr) * BKP + kh * 32 + lk];
#pragma unroll
            for (int j = 0; j < 2; ++j)
                bf[j] = *(const s16x8*)&Bs[(wc * 32 + j * 16 + lr) * BKP + kh * 32 + lk];
#pragma unroll
            for (int i = 0; i < 2; ++i)
#pragma unroll
                for (int j = 0; j < 2; ++j)
                    acc[i][j] = __builtin_amdgcn_mfma_f32_16x16x32_bf16(
                        af[i], bf[j], acc[i][j], 0, 0, 0);
        }
    }

    const int r0 = (lane >> 4) * 4;
#pragma unroll
    for (int i = 0; i < 2; ++i) {
        const int row = b * LQ + q0 + wr * 32 + i * 16 + r0;
#pragma unroll
        for (int j = 0; j < 2; ++j) {
            const int col = hcol + wc * 32 + j * 16 + lr;
#pragma unroll
            for (int r = 0; r < 4; ++r)
                ctxb[(size_t)(row + r) * DM + col] = f2b1(acc[i][j][r]);
        }
    }
}

// ============================================================
// fp32 GEMM (fallback path only)
// ============================================================
template <bool BT>
__global__ __launch_bounds__(256) void gemm64(
    const float* __restrict__ A, int lda, long aS1, long aS2,
    const float* __restrict__ Bm, int ldb, long bS1, long bS2,
    float* __restrict__ C, int ldc, long cS1, long cS2,
    const float* __restrict__ bias, int K, float alpha, int zshift)
{
    const int z = blockIdx.z;
    const long z1 = z >> zshift;
    const long z2 = z & ((1 << zshift) - 1);
    A  += z1 * aS1 + z2 * aS2;
    Bm += z1 * bS1 + z2 * bS2;
    C  += z1 * cS1 + z2 * cS2;

    const int m0 = blockIdx.y * 64, n0 = blockIdx.x * 64;
    __shared__ float As[32][68];
    __shared__ float Bs[32][68];
    const int t = threadIdx.x;
    const int ty = t >> 4, tx = t & 15;

    float acc[4][4];
#pragma unroll
    for (int i = 0; i < 4; ++i)
#pragma unroll
        for (int j = 0; j < 4; ++j) acc[i][j] = 0.0f;

    const int mA = t >> 3;
    const int kA = (t & 7) * 4;

    for (int kb = 0; kb < K; kb += 32) {
        {
            const float4 a0 = *(const float4*)&A[(size_t)(m0 + mA) * lda + kb + kA];
            const float4 a1 = *(const float4*)&A[(size_t)(m0 + mA + 32) * lda + kb + kA];
            As[kA + 0][mA] = a0.x; As[kA + 1][mA] = a0.y; As[kA + 2][mA] = a0.z; As[kA + 3][mA] = a0.w;
            As[kA + 0][mA + 32] = a1.x; As[kA + 1][mA + 32] = a1.y; As[kA + 2][mA + 32] = a1.z; As[kA + 3][mA + 32] = a1.w;
        }
        if (BT) {
            const float4 b0 = *(const float4*)&Bm[(size_t)(n0 + mA) * ldb + kb + kA];
            const float4 b1 = *(const float4*)&Bm[(size_t)(n0 + mA + 32) * ldb + kb + kA];
            Bs[kA + 0][mA] = b0.x; Bs[kA + 1][mA] = b0.y; Bs[kA + 2][mA] = b0.z; Bs[kA + 3][mA] = b0.w;
            Bs[kA + 0][mA + 32] = b1.x; Bs[kA + 1][mA + 32] = b1.y; Bs[kA + 2][mA + 32] = b1.z; Bs[kA + 3][mA + 32] = b1.w;
        } else {
            const int kB = t >> 4;
            const int nB = (t & 15) * 4;
            const float4 b0 = *(const float4*)&Bm[(size_t)(kb + kB) * ldb + n0 + nB];
            const float4 b1 = *(const float4*)&Bm[(size_t)(kb + kB + 16) * ldb + n0 + nB];
            *(float4*)&Bs[kB][nB] = b0;
            *(float4*)&Bs[kB + 16][nB] = b1;
        }
        __syncthreads();

#pragma unroll
        for (int kk = 0; kk < 32; ++kk) {
            const float4 av = *(const float4*)&As[kk][ty * 4];
            const float4 bv = *(const float4*)&Bs[kk][tx * 4];
            const float a[4] = {av.x, av.y, av.z, av.w};
            const float bb[4] = {bv.x, bv.y, bv.z, bv.w};
#pragma unroll
            for (int i = 0; i < 4; ++i)
#pragma unroll
                for (int j = 0; j < 4; ++j)
                    acc[i][j] = fmaf(a[i], bb[j], acc[i][j]);
        }
        __syncthreads();
    }

#pragma unroll
    for (int i = 0; i < 4; ++i) {
        const int row = m0 + ty * 4 + i;
        float4 o;
        o.x = acc[i][0] * alpha;
        o.y = acc[i][1] * alpha;
        o.z = acc[i][2] * alpha;
        o.w = acc[i][3] * alpha;
        if (bias) {
            o.x += bias[n0 + tx * 4 + 0];
            o.y += bias[n0 + tx * 4 + 1];
            o.z += bias[n0 + tx * 4 + 2];
            o.w += bias[n0 + tx * 4 + 3];
        }
        *(float4*)&C[(size_t)row * ldc + n0 + tx * 4] = o;
    }
}

// ============================================================
// softmax + 3x renorm (fallback path only; fp32 in-place)
// ============================================================
template <bool BF16OUT>
__global__ __launch_bounds__(256) void softmaxP_kernel(
    float* __restrict__ S, const unsigned short* __restrict__ D,
    void* __restrict__ AOut, float* __restrict__ meanOut,
    int nheads, int accumulate)
{
    const int b = blockIdx.x >> 9, q = blockIdx.x & 511;
    const int t = threadIdx.x, w = t >> 6, lane = t & 63;
    __shared__ float Pl[3][LK];
    __shared__ float part[4][LK];
    const size_t NPB = (size_t)B_ * LQ * LK;
    const size_t rowoff = ((size_t)b * LQ + q) * LK;

    for (int i = t; i < LK; i += 256) {
        Pl[0][i] = b2f1(D[rowoff + i]);
        Pl[1][i] = b2f1(D[NPB + rowoff + i]);
        Pl[2][i] = b2f1(D[2 * NPB + rowoff + i]);
    }
    __syncthreads();

    float macc[8];
#pragma unroll
    for (int j = 0; j < 8; ++j) macc[j] = 0.0f;

    for (int h = w; h < nheads; h += 4) {
        const size_t roff = (((size_t)b * nheads + h) * LQ + q) * LK;
        const float* row = S + roff;
        float v[8];
        const float4 s0 = *(const float4*)&row[lane * 8];
        const float4 s1 = *(const float4*)&row[lane * 8 + 4];
        v[0] = s0.x; v[1] = s0.y; v[2] = s0.z; v[3] = s0.w;
        v[4] = s1.x; v[5] = s1.y; v[6] = s1.z; v[7] = s1.w;
        float mx = v[0];
#pragma unroll
        for (int j = 1; j < 8; ++j) mx = fmaxf(mx, v[j]);
#pragma unroll
        for (int o = 32; o > 0; o >>= 1) mx = fmaxf(mx, __shfl_xor(mx, o));
        float zz = 0.0f;
#pragma unroll
        for (int j = 0; j < 8; ++j) { v[j] = __expf(v[j] - mx); zz += v[j]; }
#pragma unroll
        for (int o = 32; o > 0; o >>= 1) zz += __shfl_xor(zz, o);
        const float invz = 1.0f / zz;
#pragma unroll
        for (int j = 0; j < 8; ++j) v[j] *= invz;

#pragma unroll
        for (int it = 0; it < 3; ++it) {
            float s = 0.0f;
#pragma unroll
            for (int j = 0; j < 8; ++j) {
                v[j] *= Pl[it][lane * 8 + j];
                s += v[j];
            }
#pragma unroll
            for (int o = 32; o > 0; o >>= 1) s += __shfl_xor(s, o);
            const float inv = 1.0f / fmaxf(s, 1e-9f);
#pragma unroll
            for (int j = 0; j < 8; ++j) v[j] *= inv;
        }

#pragma unroll
        for (int j = 0; j < 8; ++j) macc[j] += v[j];

        if (BF16OUT) {
            unsigned short* arow = (unsigned short*)AOut + roff;
            ushort4 u0, u1;
            u0.x = f2b1(v[0]); u0.y = f2b1(v[1]); u0.z = f2b1(v[2]); u0.w = f2b1(v[3]);
            u1.x = f2b1(v[4]); u1.y = f2b1(v[5]); u1.z = f2b1(v[6]); u1.w = f2b1(v[7]);
            *(ushort4*)&arow[lane * 8] = u0;
            *(ushort4*)&arow[lane * 8 + 4] = u1;
        } else {
            float* arow = (float*)AOut + roff;
            *(float4*)&arow[lane * 8] = make_float4(v[0], v[1], v[2], v[3]);
            *(float4*)&arow[lane * 8 + 4] = make_float4(v[4], v[5], v[6], v[7]);
        }
    }

    *(float4*)&part[w][lane * 8] = make_float4(macc[0], macc[1], macc[2], macc[3]);
    *(float4*)&part[w][lane * 8 + 4] = make_float4(macc[4], macc[5], macc[6], macc[7]);
    __syncthreads();

    for (int i = t; i < LK; i += 256) {
        const float m = (part[0][i] + part[1][i] + part[2][i] + part[3][i]) * (1.0f / 16.0f);
        const size_t oi = ((size_t)b * LQ + q) * LK + i;
        meanOut[oi] = accumulate ? (meanOut[oi] + m) : m;
    }
}

// ============================================================
// Launcher
// ============================================================
extern "C" void kernel_launch(void* const* d_in, const int* in_sizes, int n_in,
                              void* d_out, int out_size, void* d_ws, size_t ws_size,
                              hipStream_t stream)
{
    const float* query  = (const float*)d_in[0];
    const float* key    = (const float*)d_in[1];
    const float* value  = (const float*)d_in[2];
    const int*   qlen   = (const int*)d_in[3];
    const int*   klen   = (const int*)d_in[4];
    const float* Wq     = (const float*)d_in[5];
    const float* bq     = (const float*)d_in[6];
    const float* Wk     = (const float*)d_in[7];
    const float* bk     = (const float*)d_in[8];
    const float* Wv     = (const float*)d_in[9];
    const float* bv     = (const float*)d_in[10];
    const float* Wo     = (const float*)d_in[11];
    const float* bo     = (const float*)d_in[12];
    const float* pscale = (const float*)d_in[13];
    const float* pbias  = (const float*)d_in[14];

    float* out     = (float*)d_out;
    float* meanOut = out + (size_t)B_ * LQ * DM;

    const size_t NQKV = (size_t)B_ * LQ * DM;      // 4,194,304
    const size_t NP   = (size_t)B_ * LQ * LK;      // 2,097,152
    const size_t NW   = (size_t)DM * DM;           // 1,048,576
    const size_t NS   = (size_t)B_ * NH * LQ * LK; // 33,554,432
    const size_t NPOS = (size_t)B_ * LQ;           // 4096
    const size_t NCOL = (size_t)B_ * 16 * LK;      // 65536

    // ---------- full-path layout ----------
    unsigned short* Dbuf = (unsigned short*)d_ws;  // 3*NP bf16
    float* posQ  = (float*)(Dbuf + 3 * NP);
    float* posK1 = posQ + NPOS;
    float* posK2 = posK1 + NPOS;
    float* rs1   = posK2 + NPOS;
    float* rd1   = rs1 + NPOS;
    float* rs2   = rd1 + NPOS;
    float* rd2   = rs2 + NPOS;
    float* colS1 = rd2 + NPOS;
    float* colD1 = colS1 + NCOL;
    float* colS2 = colD1 + NCOL;
    float* colD2 = colS2 + NCOL;
    float* fend  = colD2 + NCOL;
    unsigned short* Qb   = (unsigned short*)fend;
    unsigned short* Kb   = Qb + NQKV;
    unsigned short* Vb   = Kb + NQKV;     // unused spare (kept for layout stability)
    unsigned short* VbT  = Vb + NQKV;
    unsigned short* ctxb = VbT + NQKV;
    unsigned short* wqb  = ctxb + NQKV;
    unsigned short* wkb  = wqb + NW;
    unsigned short* wvb  = wkb + NW;
    unsigned short* wob  = wvb + NW;
    unsigned short* Ab   = wob + NW;               // NS shorts (67 MB)
    // f2b staging aliased into Ab (dead until attn_fused)
    unsigned short* xq = Ab;
    unsigned short* xk = xq + NQKV;
    unsigned short* xv = xk + NQKV;

    const size_t need_full = (size_t)((char*)(Ab + NS) - (char*)d_ws);

    if (ws_size >= need_full) {
        // positions + da tensors: 3 launches
        dim3 gDa(16, B_);
        daRow_kernel<0><<<gDa, 512, 0, stream>>>(qlen, klen, pscale, pbias,
            posQ, nullptr, posK1,
            nullptr, nullptr, nullptr, nullptr,
            rs1, rd1, colS1, colD1, Dbuf);
        daRow_kernel<1><<<gDa, 512, 0, stream>>>(qlen, klen, pscale, pbias,
            posQ, posK1, posK2,
            rs1, rd1, colS1, colD1,
            rs2, rd2, colS2, colD2, Dbuf + NP);
        daRow_kernel<2><<<gDa, 512, 0, stream>>>(qlen, klen, pscale, pbias,
            posQ, posK2, nullptr,
            rs2, rd2, colS2, colD2,
            nullptr, nullptr, nullptr, nullptr, Dbuf + 2 * NP);

        // all bf16 conversions: 1 launch
        dim3 gF(1024, 16);
        f2b_all_kernel<<<gF, 256, 0, stream>>>(query, key, value, Wq, Wk, Wv, Wo,
                                               xq, xk, xv, wqb, wkb, wvb, wob);

        // Q/K/V projections (V written transposed -> VbT, no transpose pass)
        dim3 gP(DM / 128, (B_ * LQ) / 64);
        gemm_bf16_nt<true,  false><<<gP, 256, 0, stream>>>(xq, wqb, Qb,  bq, B_ * LQ, DM, DM);
        gemm_bf16_nt<true,  false><<<gP, 256, 0, stream>>>(xk, wkb, Kb,  bk, B_ * LQ, DM, DM);
        gemm_bf16_nt<true,  true ><<<gP, 256, 0, stream>>>(xv, wvb, VbT, bv, B_ * LQ, DM, DM);

        // fused scores+softmax+renorm -> bf16 attn (all 16 heads)
        dim3 gA(LQ / 64, B_ * NH);
        attn_fused<<<gA, 512, 0, stream>>>(Qb, Kb, Dbuf, Ab);

        // meanOut from bf16 attn
        meanB_kernel<<<B_ * LQ, 256, 0, stream>>>(Ab, meanOut);

        // ctx for all heads (round-12 LDS version)
        dim3 gC(1, LQ / 64, B_ * NH);
        ctx_mfma<<<gC, 256, 0, stream>>>(Ab, VbT, ctxb);

        // out = ctx @ Wo^T + bo (fp32 out)
        gemm_bf16_nt<false, false><<<gP, 256, 0, stream>>>(ctxb, wob, out, bo, B_ * LQ, DM, DM);
        return;
    }

    // ---------- fp32 fallback (chunked per-head) ----------
    float* qbuf = (float*)d_ws;
    float* kbuf = qbuf + NQKV;
    float* vbuf = kbuf + NQKV;
    unsigned short* Dfb = (unsigned short*)(vbuf + NQKV);  // 3*NP bf16
    float* Sfb  = (float*)(Dfb + 3 * NP);        // NP
    float* ctxbuf = Sfb + NP;                    // NQKV
    float* pQ  = ctxbuf + NQKV;
    float* pK1 = pQ + NPOS;
    float* pK2 = pK1 + NPOS;
    float* frs1 = pK2 + NPOS;
    float* frd1 = frs1 + NPOS;
    float* frs2 = frd1 + NPOS;
    float* frd2 = frs2 + NPOS;
    float* fcS1 = frd2 + NPOS;
    float* fcD1 = fcS1 + NCOL;
    float* fcS2 = fcD1 + NCOL;
    float* fcD2 = fcS2 + NCOL;

    dim3 gDa(16, B_);
    daRow_kernel<0><<<gDa, 512, 0, stream>>>(qlen, klen, pscale, pbias,
        pQ, nullptr, pK1, nullptr, nullptr, nullptr, nullptr,
        frs1, frd1, fcS1, fcD1, Dfb);
    daRow_kernel<1><<<gDa, 512, 0, stream>>>(qlen, klen, pscale, pbias,
        pQ, pK1, pK2, frs1, frd1, fcS1, fcD1,
        frs2, frd2, fcS2, fcD2, Dfb + NP);
    daRow_kernel<2><<<gDa, 512, 0, stream>>>(qlen, klen, pscale, pbias,
        pQ, pK2, nullptr, frs2, frd2, fcS2, fcD2,
        nullptr, nullptr, nullptr, nullptr, Dfb + 2 * NP);

    dim3 gProj(DM / 64, (B_ * LQ) / 64, 1);
    gemm64<true><<<gProj, 256, 0, stream>>>(query, DM, 0, 0, Wq, DM, 0, 0,
                                            qbuf, DM, 0, 0, bq, DM, 1.0f, 0);
    gemm64<true><<<gProj, 256, 0, stream>>>(key, DM, 0, 0, Wk, DM, 0, 0,
                                            kbuf, DM, 0, 0, bk, DM, 1.0f, 0);
    gemm64<true><<<gProj, 256, 0, stream>>>(value, DM, 0, 0, Wv, DM, 0, 0,
                                            vbuf, DM, 0, 0, bv, DM, 1.0f, 0);
    for (int h = 0; h < NH; ++h) {
        dim3 gS2(LK / 64, LQ / 64, B_);
        gemm64<true><<<gS2, 256, 0, stream>>>(
            qbuf + h * DK, DM, (long)LQ * DM, 0,
            kbuf + h * DK, DM, (long)LK * DM, 0,
            Sfb, LK, (long)LQ * LK, 0,
            nullptr, DK, 0.125f, 0);
        softmaxP_kernel<false><<<B_ * LQ, 256, 0, stream>>>(Sfb, Dfb, Sfb, meanOut, 1, h > 0 ? 1 : 0);
        dim3 gC2(1, LQ / 64, B_);
        gemm64<false><<<gC2, 256, 0, stream>>>(
            Sfb, LK, (long)LQ * LK, 0,
            vbuf + h * DK, DM, (long)LK * DM, 0,
            ctxbuf + h * DK, DM, (long)LQ * DM, 0,
            nullptr, LK, 1.0f, 0);
    }
    dim3 gO(DM / 64, (B_ * LQ) / 64, 1);
    gemm64<true><<<gO, 256, 0, stream>>>(ctxbuf, DM, 0, 0, Wo, DM, 0, 0,
                                         out, DM, 0, 0, bo, DM, 1.0f, 0);
}

// Round 17
// 210.667 us; speedup vs baseline: 1.0826x; 1.0123x over previous
//
#include <hip/hip_runtime.h>
#include <math.h>

#define B_  8
#define LQ  512
#define LK  512
#define DM  1024
#define NH  16
#define DK  64
constexpr float PADP = 10000.0f;

typedef short s16x8 __attribute__((ext_vector_type(8)));
typedef float f32x4 __attribute__((ext_vector_type(4)));

// ============================================================
// fp32 <-> bf16 helpers
// ============================================================
__device__ inline unsigned short f2b1(float f) {
    unsigned u = __float_as_uint(f);
    unsigned r = (u + 0x7fffu + ((u >> 16) & 1u)) >> 16;
    return (unsigned short)r;
}
__device__ inline float b2f1(unsigned short h) {
    return __uint_as_float(((unsigned)h) << 16);
}

// One launch converts q,k,v (4 slots of 1M elems each) + 4 weights.
__global__ __launch_bounds__(256) void f2b_all_kernel(
    const float* __restrict__ query, const float* __restrict__ key,
    const float* __restrict__ value,
    const float* __restrict__ Wq, const float* __restrict__ Wk,
    const float* __restrict__ Wv, const float* __restrict__ Wo,
    unsigned short* __restrict__ xq, unsigned short* __restrict__ xk,
    unsigned short* __restrict__ xv,
    unsigned short* __restrict__ wqb, unsigned short* __restrict__ wkb,
    unsigned short* __restrict__ wvb, unsigned short* __restrict__ wob)
{
    const int s = blockIdx.y;
    const float* src;
    unsigned short* dst;
    if (s < 4)       { src = query + ((size_t)s << 20);       dst = xq + ((size_t)s << 20); }
    else if (s < 8)  { src = key   + ((size_t)(s - 4) << 20); dst = xk + ((size_t)(s - 4) << 20); }
    else if (s < 12) { src = value + ((size_t)(s - 8) << 20); dst = xv + ((size_t)(s - 8) << 20); }
    else {
        const int w = s - 12;
        src = (w == 0) ? Wq : (w == 1) ? Wk : (w == 2) ? Wv : Wo;
        dst = (w == 0) ? wqb : (w == 1) ? wkb : (w == 2) ? wvb : wob;
    }
    const int i = blockIdx.x * 256 + threadIdx.x;
    const float4 v = *(const float4*)&src[(size_t)i * 4];
    ushort4 o;
    o.x = f2b1(v.x); o.y = f2b1(v.y); o.z = f2b1(v.z); o.w = f2b1(v.w);
    *(ushort4*)&dst[(size_t)i * 4] = o;
}

// ============================================================
// Position pipeline: 3 launches of daRow<PHASE>. D planes bf16.
// ============================================================
template <int PHASE>
__global__ __launch_bounds__(512) void daRow_kernel(
    const int* __restrict__ qlen, const int* __restrict__ klen,
    const float* __restrict__ pscale, const float* __restrict__ pbias,
    float* __restrict__ posQ,
    const float* __restrict__ posKin, float* __restrict__ posKout,
    const float* __restrict__ rsIn, const float* __restrict__ rdIn,
    const float* __restrict__ colSIn, const float* __restrict__ colDIn,
    float* __restrict__ rsOut, float* __restrict__ rdOut,
    float* __restrict__ colSOut, float* __restrict__ colDOut,
    unsigned short* __restrict__ Dplane)
{
    constexpr int NCH = 16, QC = LQ / NCH;
    __shared__ float kpl[LK];
    __shared__ float csp[8][LK], cdp[8][LK];
    const int chunk = blockIdx.x, b = blockIdx.y;
    const int t = threadIdx.x, w = t >> 6, lane = t & 63;

    float scale = 0.0f, bias = 0.0f;
    if (PHASE == 0) { scale = pscale[0]; bias = pbias[0]; }

    if (PHASE == 0) {
        const int kl = klen[b];
        const float Lf = (float)kl;
        const float step = (Lf > 1.0f) ? Lf / (Lf - 1.0f) : 0.0f;
        const float pos = (-Lf * 0.5f + (float)t * step) * scale + bias;
        const float kv = (t >= kl) ? PADP : pos;
        kpl[t] = kv;
        if (chunk == 0) posKout[b * LK + t] = kv;
    } else {
        float colsum = 0.0f, coldot = 0.0f;
#pragma unroll
        for (int c = 0; c < NCH; ++c) {
            colsum += colSIn[((size_t)b * NCH + c) * LK + t];
            coldot += colDIn[((size_t)b * NCH + c) * LK + t];
        }
        const float prev = posKin[b * LK + t];
        const float kv = (prev >= 1000.0f) ? PADP : coldot / fmaxf(colsum, 1e-9f);
        kpl[t] = kv;
        if (PHASE == 1 && chunk == 0) posKout[b * LK + t] = kv;
    }
    __syncthreads();

    float cs[8] = {0,0,0,0,0,0,0,0}, cd[8] = {0,0,0,0,0,0,0,0};
    unsigned short* Dbb = Dplane + (size_t)b * LQ * LK;

    for (int qi = chunk * QC + w; qi < chunk * QC + QC; qi += 8) {
        float qpv;
        if (PHASE == 0) {
            const int ql = qlen[b];
            const float Lf = (float)ql;
            const float step = (Lf > 1.0f) ? Lf / (Lf - 1.0f) : 0.0f;
            qpv = (qi >= ql) ? PADP : (-Lf * 0.5f + (float)qi * step) * scale + bias;
            if (lane == 0) posQ[b * LQ + qi] = qpv;
        } else {
            const float prev = posQ[b * LQ + qi];
            qpv = (prev >= 1000.0f) ? PADP
                : rdIn[b * LQ + qi] / fmaxf(rsIn[b * LQ + qi], 1e-9f);
            if (PHASE == 1 && lane == 0) posQ[b * LQ + qi] = qpv;
        }
        const bool qpad = (qpv >= 1000.0f);
        float rsum = 0.0f, rdot = 0.0f;
#pragma unroll
        for (int c = 0; c < 8; ++c) {
            const int k = lane + 64 * c;
            const float kpv = kpl[k];
            const float d = qpv - kpv;
            float e = (qpad || (kpv >= 1000.0f)) ? 0.0f : __expf(-0.5f * d * d);
            if (PHASE < 2) { rsum += e; rdot += e * kpv; cs[c] += e; cd[c] += e * qpv; }
            Dbb[(size_t)qi * LK + k] = f2b1(e);
        }
        if (PHASE < 2) {
#pragma unroll
            for (int o = 32; o > 0; o >>= 1) {
                rsum += __shfl_xor(rsum, o);
                rdot += __shfl_xor(rdot, o);
            }
            if (lane == 0) { rsOut[b * LQ + qi] = rsum; rdOut[b * LQ + qi] = rdot; }
        }
    }
    if (PHASE < 2) {
#pragma unroll
        for (int c = 0; c < 8; ++c) {
            csp[w][lane + 64 * c] = cs[c];
            cdp[w][lane + 64 * c] = cd[c];
        }
        __syncthreads();
        float s = 0.0f, dd = 0.0f;
        for (int ww = 0; ww < 8; ++ww) { s += csp[ww][t]; dd += cdp[ww][t]; }
        colSOut[((size_t)b * NCH + chunk) * LK + t] = s;
        colDOut[((size_t)b * NCH + chunk) * LK + t] = dd;
    }
}

// ============================================================
// bf16 MFMA GEMM v2: C = (A @ Bt^T) + bias. 64x128 tile, 4 waves,
// BK=32, global_load_lds staging (width 16, linear LDS).
// OB: bf16 output. OT: write transposed C[col*M+row] (bf16 only).
// ============================================================
template <bool OB, bool OT>
__global__ __launch_bounds__(256) void gemm_bf16_nt(
    const unsigned short* __restrict__ A,
    const unsigned short* __restrict__ Bt,
    void* __restrict__ Cv,
    const float* __restrict__ bias,
    int M, int N, int K)
{
    __shared__ short As[64 * 32];    // 4 KB
    __shared__ short Bs[128 * 32];   // 8 KB
    const int m0 = blockIdx.y * 64, n0 = blockIdx.x * 128;
    const int t = threadIdx.x;
    const int wid = t >> 6, lane = t & 63;
    const int wr = wid >> 1, wc = wid & 1;
    const int lr = lane & 15, lk = (lane >> 4) * 8;

    f32x4 acc[2][4] = {};

    const int srow = lane >> 2;          // 0..15
    const int scol = (lane & 3) * 8;     // shorts: 0,8,16,24

    for (int kb = 0; kb < K; kb += 32) {
        __syncthreads();
        {
            const unsigned short* g = &A[(size_t)(m0 + wid * 16 + srow) * K + kb + scol];
            __builtin_amdgcn_global_load_lds((const unsigned*)g,
                (unsigned*)&As[(wid * 16) * 32], 16, 0, 0);
        }
#pragma unroll
        for (int u = 0; u < 2; ++u) {
            const unsigned short* g = &Bt[(size_t)(n0 + wid * 32 + u * 16 + srow) * K + kb + scol];
            __builtin_amdgcn_global_load_lds((const unsigned*)g,
                (unsigned*)&Bs[(wid * 32 + u * 16) * 32], 16, 0, 0);
        }
        __syncthreads();

        s16x8 af[2], bf[4];
#pragma unroll
        for (int i = 0; i < 2; ++i)
            af[i] = *(const s16x8*)&As[(wr * 32 + i * 16 + lr) * 32 + lk];
#pragma unroll
        for (int j = 0; j < 4; ++j)
            bf[j] = *(const s16x8*)&Bs[(wc * 64 + j * 16 + lr) * 32 + lk];
#pragma unroll
        for (int i = 0; i < 2; ++i)
#pragma unroll
            for (int j = 0; j < 4; ++j)
                acc[i][j] = __builtin_amdgcn_mfma_f32_16x16x32_bf16(
                    af[i], bf[j], acc[i][j], 0, 0, 0);
    }

    const int r0 = (lane >> 4) * 4;
#pragma unroll
    for (int i = 0; i < 2; ++i) {
        const int row = m0 + wr * 32 + i * 16 + r0;
#pragma unroll
        for (int j = 0; j < 4; ++j) {
            const int col = n0 + wc * 64 + j * 16 + lr;
            const float bvv = bias ? bias[col] : 0.0f;
#pragma unroll
            for (int r = 0; r < 4; ++r) {
                const float val = acc[i][j][r] + bvv;
                if (OT)      ((unsigned short*)Cv)[(size_t)col * M + row + r] = f2b1(val);
                else if (OB) ((unsigned short*)Cv)[(size_t)(row + r) * N + col] = f2b1(val);
                else         ((float*)Cv)[(size_t)(row + r) * N + col] = val;
            }
        }
    }
}

// ============================================================
// Fused scores + softmax + 3x da-renorm, v2 hybrid.
// Phase C processes rows in PAIRS for 2-way ILP on the
// shfl-reduction chains and D-load latency (row math identical).
// ============================================================
__global__ __launch_bounds__(512) void attn_fused(
    const unsigned short* __restrict__ Qb,
    const unsigned short* __restrict__ Kb,
    const unsigned short* __restrict__ D,
    unsigned short* __restrict__ Ab)
{
    constexpr int KP = 72;    // Q/K staging pitch (shorts)
    constexpr int SP = 520;   // e-tile pitch (shorts)
    __shared__ short pool[64 * SP];   // 66560 B; Qs/Ks alias inside
    __shared__ float red[8][64];
    short* Qs = pool;
    short* Ks = pool + 4608;

    const int z = blockIdx.y;
    const int b = z >> 4, h = z & 15;
    const int q0 = blockIdx.x * 64;
    const int t = threadIdx.x;
    const int wid = t >> 6, lane = t & 63;
    const int lr = lane & 15, lkq = (lane >> 4) * 8;
    const int rbase = (lane >> 4) * 4;

    // ---- Phase A: load Q tile, MFMA scores ----
    {
        const int row = t >> 3, seg = (t & 7) * 8;
        *(uint4*)&Qs[row * KP + seg] =
            *(const uint4*)&Qb[((size_t)(b * LQ + q0 + row)) * DM + h * DK + seg];
    }

    f32x4 acc[2][4][2] = {};   // [kh][i][j]

#pragma unroll
    for (int kh = 0; kh < 2; ++kh) {
        __syncthreads();
        {
            const int row = t >> 1, seg = (t & 1) * 32;
            const unsigned short* src =
                &Kb[((size_t)(b * LK + kh * 256 + row)) * DM + h * DK + seg];
#pragma unroll
            for (int s = 0; s < 4; ++s)
                *(uint4*)&Ks[row * KP + seg + s * 8] = *(const uint4*)(src + s * 8);
        }
        __syncthreads();

#pragma unroll
        for (int ks = 0; ks < 2; ++ks) {
            s16x8 af[4], bf[2];
#pragma unroll
            for (int i = 0; i < 4; ++i)
                af[i] = *(const s16x8*)&Qs[(i * 16 + lr) * KP + ks * 32 + lkq];
#pragma unroll
            for (int j = 0; j < 2; ++j)
                bf[j] = *(const s16x8*)&Ks[(wid * 32 + j * 16 + lr) * KP + ks * 32 + lkq];
#pragma unroll
            for (int i = 0; i < 4; ++i)
#pragma unroll
                for (int j = 0; j < 2; ++j)
                    acc[kh][i][j] = __builtin_amdgcn_mfma_f32_16x16x32_bf16(
                        af[i], bf[j], acc[kh][i][j], 0, 0, 0);
        }
    }

    // ---- row max (only cross-lane reduce in MFMA layout) ----
    float M[4][4];
#pragma unroll
    for (int i = 0; i < 4; ++i)
#pragma unroll
        for (int r = 0; r < 4; ++r) {
            float m = acc[0][i][0][r];
            m = fmaxf(m, acc[0][i][1][r]);
            m = fmaxf(m, acc[1][i][0][r]);
            m = fmaxf(m, acc[1][i][1][r]);
#pragma unroll
            for (int o = 1; o < 16; o <<= 1)
                m = fmaxf(m, __shfl_xor(m, o));
            M[i][r] = m;
        }
    __syncthreads();           // MFMA reads of Qs/Ks complete
    if (lr == 0) {
#pragma unroll
        for (int i = 0; i < 4; ++i)
#pragma unroll
            for (int r = 0; r < 4; ++r)
                red[wid][i * 16 + rbase + r] = M[i][r];
    }
    __syncthreads();
#pragma unroll
    for (int i = 0; i < 4; ++i)
#pragma unroll
        for (int r = 0; r < 4; ++r) {
            float m = red[0][i * 16 + rbase + r];
#pragma unroll
            for (int ww = 1; ww < 8; ++ww)
                m = fmaxf(m, red[ww][i * 16 + rbase + r]);
            M[i][r] = m;
        }

    // ---- Phase B: exp -> bf16 e-tile in LDS (overwrites Qs/Ks) ----
#pragma unroll
    for (int kh = 0; kh < 2; ++kh)
#pragma unroll
        for (int i = 0; i < 4; ++i)
#pragma unroll
            for (int j = 0; j < 2; ++j) {
                const int col = kh * 256 + wid * 32 + j * 16 + lr;
#pragma unroll
                for (int r = 0; r < 4; ++r) {
                    const int row = i * 16 + rbase + r;
                    const float e = __expf((acc[kh][i][j][r] - M[i][r]) * 0.125f);
                    pool[row * SP + col] = (short)f2b1(e);
                }
            }
    __syncthreads();

    // ---- Phase C: row-pair-parallel softmax-z + 3x da-renorm ----
#pragma unroll
    for (int rp = 0; rp < 4; ++rp) {
        const int rr0 = wid * 8 + rp * 2;
        const int rr1 = rr0 + 1;
        float v0[8], v1[8];
        {
            const uint4 e0 = *(const uint4*)&pool[rr0 * SP + lane * 8];
            const uint4 e1 = *(const uint4*)&pool[rr1 * SP + lane * 8];
            const unsigned short* p0 = (const unsigned short*)&e0;
            const unsigned short* p1 = (const unsigned short*)&e1;
#pragma unroll
            for (int j = 0; j < 8; ++j) { v0[j] = b2f1(p0[j]); v1[j] = b2f1(p1[j]); }
        }
        float s0 = 0.0f, s1 = 0.0f;
#pragma unroll
        for (int j = 0; j < 8; ++j) { s0 += v0[j]; s1 += v1[j]; }
#pragma unroll
        for (int o = 32; o > 0; o >>= 1) {
            s0 += __shfl_xor(s0, o);
            s1 += __shfl_xor(s1, o);
        }
        const float iz0 = 1.0f / s0, iz1 = 1.0f / s1;
#pragma unroll
        for (int j = 0; j < 8; ++j) { v0[j] *= iz0; v1[j] *= iz1; }

#pragma unroll
        for (int it = 0; it < 3; ++it) {
            const size_t dbase = (((size_t)it * B_ + b) * LQ + q0);
            const uint4 d0 = *(const uint4*)&D[(dbase + rr0) * LK + lane * 8];
            const uint4 d1 = *(const uint4*)&D[(dbase + rr1) * LK + lane * 8];
            const unsigned short* p0 = (const unsigned short*)&d0;
            const unsigned short* p1 = (const unsigned short*)&d1;
            float t0 = 0.0f, t1 = 0.0f;
#pragma unroll
            for (int j = 0; j < 8; ++j) {
                v0[j] *= b2f1(p0[j]); t0 += v0[j];
                v1[j] *= b2f1(p1[j]); t1 += v1[j];
            }
#pragma unroll
            for (int o = 32; o > 0; o >>= 1) {
                t0 += __shfl_xor(t0, o);
                t1 += __shfl_xor(t1, o);
            }
            const float i0 = 1.0f / fmaxf(t0, 1e-9f);
            const float i1 = 1.0f / fmaxf(t1, 1e-9f);
#pragma unroll
            for (int j = 0; j < 8; ++j) { v0[j] *= i0; v1[j] *= i1; }
        }

        ushort4 a0, a1, b0, b1;
        a0.x = f2b1(v0[0]); a0.y = f2b1(v0[1]); a0.z = f2b1(v0[2]); a0.w = f2b1(v0[3]);
        a1.x = f2b1(v0[4]); a1.y = f2b1(v0[5]); a1.z = f2b1(v0[6]); a1.w = f2b1(v0[7]);
        b0.x = f2b1(v1[0]); b0.y = f2b1(v1[1]); b0.z = f2b1(v1[2]); b0.w = f2b1(v1[3]);
        b1.x = f2b1(v1[4]); b1.y = f2b1(v1[5]); b1.z = f2b1(v1[6]); b1.w = f2b1(v1[7]);
        unsigned short* ar0 = Ab + ((size_t)z * LQ + q0 + rr0) * LK + lane * 8;
        unsigned short* ar1 = Ab + ((size_t)z * LQ + q0 + rr1) * LK + lane * 8;
        *(ushort4*)&ar0[0] = a0;
        *(ushort4*)&ar0[4] = a1;
        *(ushort4*)&ar1[0] = b0;
        *(ushort4*)&ar1[4] = b1;
    }
}

// ============================================================
// meanOut[b][q][k] = (1/16) * sum_h Ab[b*16+h][q][k]
// ============================================================
__global__ __launch_bounds__(256) void meanB_kernel(
    const unsigned short* __restrict__ Ab, float* __restrict__ meanOut)
{
    const int b = blockIdx.x >> 9, q = blockIdx.x & 511;
    const int t = threadIdx.x;
    const int c0 = t * 2;
    float s0 = 0.0f, s1 = 0.0f;
#pragma unroll
    for (int h = 0; h < 16; ++h) {
        const unsigned short* row = Ab + (((size_t)(b * 16 + h)) * LQ + q) * LK;
        const unsigned v = *(const unsigned*)&row[c0];
        s0 += b2f1((unsigned short)(v & 0xffff));
        s1 += b2f1((unsigned short)(v >> 16));
    }
    float* o = meanOut + ((size_t)b * LQ + q) * LK + c0;
    o[0] = s0 * (1.0f / 16.0f);
    o[1] = s1 * (1.0f / 16.0f);
}

// ============================================================
// ctx (round-12 proven LDS version): ctxb[b,q,h*64+d] =
// bf16( sum_k Ab[z,q,k] * V[b,k,h*64+d] ), z = b*16+h.
// 64x64 tile, 4 waves, BK=64.
// ============================================================
__global__ __launch_bounds__(256) void ctx_mfma(
    const unsigned short* __restrict__ Ab,
    const unsigned short* __restrict__ VbT,
    unsigned short* __restrict__ ctxb)
{
    constexpr int BKP = 72;
    __shared__ short As[64 * BKP];
    __shared__ short Bs[64 * BKP];
    const int z = blockIdx.z;
    const int b = z >> 4, h = z & 15;
    const int hcol = h * DK;
    const int q0 = blockIdx.y * 64;
    const int t = threadIdx.x;
    const int wid = t >> 6, lane = t & 63;
    const int wr = wid >> 1, wc = wid & 1;
    const int lr = lane & 15, lk = (lane >> 4) * 8;

    const unsigned short* Abase = Ab + ((size_t)z * LQ + q0) * LK;
    const unsigned short* Bbase = VbT + (size_t)hcol * (B_ * LK) + (size_t)b * LK;

    f32x4 acc[2][2] = {};
    const int srow = t >> 2, sseg = (t & 3) * 16;

    for (int kb = 0; kb < LK; kb += 64) {
        const uint4 a0 = *(const uint4*)&Abase[(size_t)srow * LK + kb + sseg];
        const uint4 a1 = *(const uint4*)&Abase[(size_t)srow * LK + kb + sseg + 8];
        const uint4 b0 = *(const uint4*)&Bbase[(size_t)srow * (B_ * LK) + kb + sseg];
        const uint4 b1 = *(const uint4*)&Bbase[(size_t)srow * (B_ * LK) + kb + sseg + 8];
        __syncthreads();
        *(uint4*)&As[srow * BKP + sseg] = a0;
        *(uint4*)&As[srow * BKP + sseg + 8] = a1;
        *(uint4*)&Bs[srow * BKP + sseg] = b0;
        *(uint4*)&Bs[srow * BKP + sseg + 8] = b1;
        __syncthreads();

#pragma unroll
        for (int kh = 0; kh < 2; ++kh) {
            s16x8 af[2], bf[2];
#pragma unroll
            for (int i = 0; i < 2; ++i)
                af[i] = *(const s16x8*)&As[(wr * 32 + i * 16 + lr) * BKP + kh * 32 + lk];
#pragma unroll
            for (int j = 0; j < 2; ++j)
                bf[j] = *(const s16x8*)&Bs[(wc * 32 + j * 16 + lr) * BKP + kh * 32 + lk];
#pragma unroll
            for (int i = 0; i < 2; ++i)
#pragma unroll
                for (int j = 0; j < 2; ++j)
                    acc[i][j] = __builtin_amdgcn_mfma_f32_16x16x32_bf16(
                        af[i], bf[j], acc[i][j], 0, 0, 0);
        }
    }

    const int r0 = (lane >> 4) * 4;
#pragma unroll
    for (int i = 0; i < 2; ++i) {
        const int row = b * LQ + q0 + wr * 32 + i * 16 + r0;
#pragma unroll
        for (int j = 0; j < 2; ++j) {
            const int col = hcol + wc * 32 + j * 16 + lr;
#pragma unroll
            for (int r = 0; r < 4; ++r)
                ctxb[(size_t)(row + r) * DM + col] = f2b1(acc[i][j][r]);
        }
    }
}

// ============================================================
// fp32 GEMM (fallback path only)
// ============================================================
template <bool BT>
__global__ __launch_bounds__(256) void gemm64(
    const float* __restrict__ A, int lda, long aS1, long aS2,
    const float* __restrict__ Bm, int ldb, long bS1, long bS2,
    float* __restrict__ C, int ldc, long cS1, long cS2,
    const float* __restrict__ bias, int K, float alpha, int zshift)
{
    const int z = blockIdx.z;
    const long z1 = z >> zshift;
    const long z2 = z & ((1 << zshift) - 1);
    A  += z1 * aS1 + z2 * aS2;
    Bm += z1 * bS1 + z2 * bS2;
    C  += z1 * cS1 + z2 * cS2;

    const int m0 = blockIdx.y * 64, n0 = blockIdx.x * 64;
    __shared__ float As[32][68];
    __shared__ float Bs[32][68];
    const int t = threadIdx.x;
    const int ty = t >> 4, tx = t & 15;

    float acc[4][4];
#pragma unroll
    for (int i = 0; i < 4; ++i)
#pragma unroll
        for (int j = 0; j < 4; ++j) acc[i][j] = 0.0f;

    const int mA = t >> 3;
    const int kA = (t & 7) * 4;

    for (int kb = 0; kb < K; kb += 32) {
        {
            const float4 a0 = *(const float4*)&A[(size_t)(m0 + mA) * lda + kb + kA];
            const float4 a1 = *(const float4*)&A[(size_t)(m0 + mA + 32) * lda + kb + kA];
            As[kA + 0][mA] = a0.x; As[kA + 1][mA] = a0.y; As[kA + 2][mA] = a0.z; As[kA + 3][mA] = a0.w;
            As[kA + 0][mA + 32] = a1.x; As[kA + 1][mA + 32] = a1.y; As[kA + 2][mA + 32] = a1.z; As[kA + 3][mA + 32] = a1.w;
        }
        if (BT) {
            const float4 b0 = *(const float4*)&Bm[(size_t)(n0 + mA) * ldb + kb + kA];
            const float4 b1 = *(const float4*)&Bm[(size_t)(n0 + mA + 32) * ldb + kb + kA];
            Bs[kA + 0][mA] = b0.x; Bs[kA + 1][mA] = b0.y; Bs[kA + 2][mA] = b0.z; Bs[kA + 3][mA] = b0.w;
            Bs[kA + 0][mA + 32] = b1.x; Bs[kA + 1][mA + 32] = b1.y; Bs[kA + 2][mA + 32] = b1.z; Bs[kA + 3][mA + 32] = b1.w;
        } else {
            const int kB = t >> 4;
            const int nB = (t & 15) * 4;
            const float4 b0 = *(const float4*)&Bm[(size_t)(kb + kB) * ldb + n0 + nB];
            const float4 b1 = *(const float4*)&Bm[(size_t)(kb + kB + 16) * ldb + n0 + nB];
            *(float4*)&Bs[kB][nB] = b0;
            *(float4*)&Bs[kB + 16][nB] = b1;
        }
        __syncthreads();

#pragma unroll
        for (int kk = 0; kk < 32; ++kk) {
            const float4 av = *(const float4*)&As[kk][ty * 4];
            const float4 bv = *(const float4*)&Bs[kk][tx * 4];
            const float a[4] = {av.x, av.y, av.z, av.w};
            const float bb[4] = {bv.x, bv.y, bv.z, bv.w};
#pragma unroll
            for (int i = 0; i < 4; ++i)
#pragma unroll
                for (int j = 0; j < 4; ++j)
                    acc[i][j] = fmaf(a[i], bb[j], acc[i][j]);
        }
        __syncthreads();
    }

#pragma unroll
    for (int i = 0; i < 4; ++i) {
        const int row = m0 + ty * 4 + i;
        float4 o;
        o.x = acc[i][0] * alpha;
        o.y = acc[i][1] * alpha;
        o.z = acc[i][2] * alpha;
        o.w = acc[i][3] * alpha;
        if (bias) {
            o.x += bias[n0 + tx * 4 + 0];
            o.y += bias[n0 + tx * 4 + 1];
            o.z += bias[n0 + tx * 4 + 2];
            o.w += bias[n0 + tx * 4 + 3];
        }
        *(float4*)&C[(size_t)row * ldc + n0 + tx * 4] = o;
    }
}

// ============================================================
// softmax + 3x renorm (fallback path only; fp32 in-place)
// ============================================================
template <bool BF16OUT>
__global__ __launch_bounds__(256) void softmaxP_kernel(
    float* __restrict__ S, const unsigned short* __restrict__ D,
    void* __restrict__ AOut, float* __restrict__ meanOut,
    int nheads, int accumulate)
{
    const int b = blockIdx.x >> 9, q = blockIdx.x & 511;
    const int t = threadIdx.x, w = t >> 6, lane = t & 63;
    __shared__ float Pl[3][LK];
    __shared__ float part[4][LK];
    const size_t NPB = (size_t)B_ * LQ * LK;
    const size_t rowoff = ((size_t)b * LQ + q) * LK;

    for (int i = t; i < LK; i += 256) {
        Pl[0][i] = b2f1(D[rowoff + i]);
        Pl[1][i] = b2f1(D[NPB + rowoff + i]);
        Pl[2][i] = b2f1(D[2 * NPB + rowoff + i]);
    }
    __syncthreads();

    float macc[8];
#pragma unroll
    for (int j = 0; j < 8; ++j) macc[j] = 0.0f;

    for (int h = w; h < nheads; h += 4) {
        const size_t roff = (((size_t)b * nheads + h) * LQ + q) * LK;
        const float* row = S + roff;
        float v[8];
        const float4 s0 = *(const float4*)&row[lane * 8];
        const float4 s1 = *(const float4*)&row[lane * 8 + 4];
        v[0] = s0.x; v[1] = s0.y; v[2] = s0.z; v[3] = s0.w;
        v[4] = s1.x; v[5] = s1.y; v[6] = s1.z; v[7] = s1.w;
        float mx = v[0];
#pragma unroll
        for (int j = 1; j < 8; ++j) mx = fmaxf(mx, v[j]);
#pragma unroll
        for (int o = 32; o > 0; o >>= 1) mx = fmaxf(mx, __shfl_xor(mx, o));
        float zz = 0.0f;
#pragma unroll
        for (int j = 0; j < 8; ++j) { v[j] = __expf(v[j] - mx); zz += v[j]; }
#pragma unroll
        for (int o = 32; o > 0; o >>= 1) zz += __shfl_xor(zz, o);
        const float invz = 1.0f / zz;
#pragma unroll
        for (int j = 0; j < 8; ++j) v[j] *= invz;

#pragma unroll
        for (int it = 0; it < 3; ++it) {
            float s = 0.0f;
#pragma unroll
            for (int j = 0; j < 8; ++j) {
                v[j] *= Pl[it][lane * 8 + j];
                s += v[j];
            }
#pragma unroll
            for (int o = 32; o > 0; o >>= 1) s += __shfl_xor(s, o);
            const float inv = 1.0f / fmaxf(s, 1e-9f);
#pragma unroll
            for (int j = 0; j < 8; ++j) v[j] *= inv;
        }

#pragma unroll
        for (int j = 0; j < 8; ++j) macc[j] += v[j];

        if (BF16OUT) {
            unsigned short* arow = (unsigned short*)AOut + roff;
            ushort4 u0, u1;
            u0.x = f2b1(v[0]); u0.y = f2b1(v[1]); u0.z = f2b1(v[2]); u0.w = f2b1(v[3]);
            u1.x = f2b1(v[4]); u1.y = f2b1(v[5]); u1.z = f2b1(v[6]); u1.w = f2b1(v[7]);
            *(ushort4*)&arow[lane * 8] = u0;
            *(ushort4*)&arow[lane * 8 + 4] = u1;
        } else {
            float* arow = (float*)AOut + roff;
            *(float4*)&arow[lane * 8] = make_float4(v[0], v[1], v[2], v[3]);
            *(float4*)&arow[lane * 8 + 4] = make_float4(v[4], v[5], v[6], v[7]);
        }
    }

    *(float4*)&part[w][lane * 8] = make_float4(macc[0], macc[1], macc[2], macc[3]);
    *(float4*)&part[w][lane * 8 + 4] = make_float4(macc[4], macc[5], macc[6], macc[7]);
    __syncthreads();

    for (int i = t; i < LK; i += 256) {
        const float m = (part[0][i] + part[1][i] + part[2][i] + part[3][i]) * (1.0f / 16.0f);
        const size_t oi = ((size_t)b * LQ + q) * LK + i;
        meanOut[oi] = accumulate ? (meanOut[oi] + m) : m;
    }
}

// ============================================================
// Launcher
// ============================================================
extern "C" void kernel_launch(void* const* d_in, const int* in_sizes, int n_in,
                              void* d_out, int out_size, void* d_ws, size_t ws_size,
                              hipStream_t stream)
{
    const float* query  = (const float*)d_in[0];
    const float* key    = (const float*)d_in[1];
    const float* value  = (const float*)d_in[2];
    const int*   qlen   = (const int*)d_in[3];
    const int*   klen   = (const int*)d_in[4];
    const float* Wq     = (const float*)d_in[5];
    const float* bq     = (const float*)d_in[6];
    const float* Wk     = (const float*)d_in[7];
    const float* bk     = (const float*)d_in[8];
    const float* Wv     = (const float*)d_in[9];
    const float* bv     = (const float*)d_in[10];
    const float* Wo     = (const float*)d_in[11];
    const float* bo     = (const float*)d_in[12];
    const float* pscale = (const float*)d_in[13];
    const float* pbias  = (const float*)d_in[14];

    float* out     = (float*)d_out;
    float* meanOut = out + (size_t)B_ * LQ * DM;

    const size_t NQKV = (size_t)B_ * LQ * DM;      // 4,194,304
    const size_t NP   = (size_t)B_ * LQ * LK;      // 2,097,152
    const size_t NW   = (size_t)DM * DM;           // 1,048,576
    const size_t NS   = (size_t)B_ * NH * LQ * LK; // 33,554,432
    const size_t NPOS = (size_t)B_ * LQ;           // 4096
    const size_t NCOL = (size_t)B_ * 16 * LK;      // 65536

    // ---------- full-path layout ----------
    unsigned short* Dbuf = (unsigned short*)d_ws;  // 3*NP bf16
    float* posQ  = (float*)(Dbuf + 3 * NP);
    float* posK1 = posQ + NPOS;
    float* posK2 = posK1 + NPOS;
    float* rs1   = posK2 + NPOS;
    float* rd1   = rs1 + NPOS;
    float* rs2   = rd1 + NPOS;
    float* rd2   = rs2 + NPOS;
    float* colS1 = rd2 + NPOS;
    float* colD1 = colS1 + NCOL;
    float* colS2 = colD1 + NCOL;
    float* colD2 = colS2 + NCOL;
    float* fend  = colD2 + NCOL;
    unsigned short* Qb   = (unsigned short*)fend;
    unsigned short* Kb   = Qb + NQKV;
    unsigned short* Vb   = Kb + NQKV;     // unused spare (kept for layout stability)
    unsigned short* VbT  = Vb + NQKV;
    unsigned short* ctxb = VbT + NQKV;
    unsigned short* wqb  = ctxb + NQKV;
    unsigned short* wkb  = wqb + NW;
    unsigned short* wvb  = wkb + NW;
    unsigned short* wob  = wvb + NW;
    unsigned short* Ab   = wob + NW;               // NS shorts (67 MB)
    // f2b staging aliased into Ab (dead until attn_fused)
    unsigned short* xq = Ab;
    unsigned short* xk = xq + NQKV;
    unsigned short* xv = xk + NQKV;

    const size_t need_full = (size_t)((char*)(Ab + NS) - (char*)d_ws);

    if (ws_size >= need_full) {
        // positions + da tensors: 3 launches
        dim3 gDa(16, B_);
        daRow_kernel<0><<<gDa, 512, 0, stream>>>(qlen, klen, pscale, pbias,
            posQ, nullptr, posK1,
            nullptr, nullptr, nullptr, nullptr,
            rs1, rd1, colS1, colD1, Dbuf);
        daRow_kernel<1><<<gDa, 512, 0, stream>>>(qlen, klen, pscale, pbias,
            posQ, posK1, posK2,
            rs1, rd1, colS1, colD1,
            rs2, rd2, colS2, colD2, Dbuf + NP);
        daRow_kernel<2><<<gDa, 512, 0, stream>>>(qlen, klen, pscale, pbias,
            posQ, posK2, nullptr,
            rs2, rd2, colS2, colD2,
            nullptr, nullptr, nullptr, nullptr, Dbuf + 2 * NP);

        // all bf16 conversions: 1 launch
        dim3 gF(1024, 16);
        f2b_all_kernel<<<gF, 256, 0, stream>>>(query, key, value, Wq, Wk, Wv, Wo,
                                               xq, xk, xv, wqb, wkb, wvb, wob);

        // Q/K/V projections (V written transposed -> VbT, no transpose pass)
        dim3 gP(DM / 128, (B_ * LQ) / 64);
        gemm_bf16_nt<true,  false><<<gP, 256, 0, stream>>>(xq, wqb, Qb,  bq, B_ * LQ, DM, DM);
        gemm_bf16_nt<true,  false><<<gP, 256, 0, stream>>>(xk, wkb, Kb,  bk, B_ * LQ, DM, DM);
        gemm_bf16_nt<true,  true ><<<gP, 256, 0, stream>>>(xv, wvb, VbT, bv, B_ * LQ, DM, DM);

        // fused scores+softmax+renorm -> bf16 attn (all 16 heads)
        dim3 gA(LQ / 64, B_ * NH);
        attn_fused<<<gA, 512, 0, stream>>>(Qb, Kb, Dbuf, Ab);

        // meanOut from bf16 attn
        meanB_kernel<<<B_ * LQ, 256, 0, stream>>>(Ab, meanOut);

        // ctx for all heads (round-12 LDS version)
        dim3 gC(1, LQ / 64, B_ * NH);
        ctx_mfma<<<gC, 256, 0, stream>>>(Ab, VbT, ctxb);

        // out = ctx @ Wo^T + bo (fp32 out)
        gemm_bf16_nt<false, false><<<gP, 256, 0, stream>>>(ctxb, wob, out, bo, B_ * LQ, DM, DM);
        return;
    }

    // ---------- fp32 fallback (chunked per-head) ----------
    float* qbuf = (float*)d_ws;
    float* kbuf = qbuf + NQKV;
    float* vbuf = kbuf + NQKV;
    unsigned short* Dfb = (unsigned short*)(vbuf + NQKV);  // 3*NP bf16
    float* Sfb  = (float*)(Dfb + 3 * NP);        // NP
    float* ctxbuf = Sfb + NP;                    // NQKV
    float* pQ  = ctxbuf + NQKV;
    float* pK1 = pQ + NPOS;
    float* pK2 = pK1 + NPOS;
    float* frs1 = pK2 + NPOS;
    float* frd1 = frs1 + NPOS;
    float* frs2 = frd1 + NPOS;
    float* frd2 = frs2 + NPOS;
    float* fcS1 = frd2 + NPOS;
    float* fcD1 = fcS1 + NCOL;
    float* fcS2 = fcD1 + NCOL;
    float* fcD2 = fcS2 + NCOL;

    dim3 gDa(16, B_);
    daRow_kernel<0><<<gDa, 512, 0, stream>>>(qlen, klen, pscale, pbias,
        pQ, nullptr, pK1, nullptr, nullptr, nullptr, nullptr,
        frs1, frd1, fcS1, fcD1, Dfb);
    daRow_kernel<1><<<gDa, 512, 0, stream>>>(qlen, klen, pscale, pbias,
        pQ, pK1, pK2, frs1, frd1, fcS1, fcD1,
        frs2, frd2, fcS2, fcD2, Dfb + NP);
    daRow_kernel<2><<<gDa, 512, 0, stream>>>(qlen, klen, pscale, pbias,
        pQ, pK2, nullptr, frs2, frd2, fcS2, fcD2,
        nullptr, nullptr, nullptr, nullptr, Dfb + 2 * NP);

    dim3 gProj(DM / 64, (B_ * LQ) / 64, 1);
    gemm64<true><<<gProj, 256, 0, stream>>>(query, DM, 0, 0, Wq, DM, 0, 0,
                                            qbuf, DM, 0, 0, bq, DM, 1.0f, 0);
    gemm64<true><<<gProj, 256, 0, stream>>>(key, DM, 0, 0, Wk, DM, 0, 0,
                                            kbuf, DM, 0, 0, bk, DM, 1.0f, 0);
    gemm64<true><<<gProj, 256, 0, stream>>>(value, DM, 0, 0, Wv, DM, 0, 0,
                                            vbuf, DM, 0, 0, bv, DM, 1.0f, 0);
    for (int h = 0; h < NH; ++h) {
        dim3 gS2(LK / 64, LQ / 64, B_);
        gemm64<true><<<gS2, 256, 0, stream>>>(
            qbuf + h * DK, DM, (long)LQ * DM, 0,
            kbuf + h * DK, DM, (long)LK * DM, 0,
            Sfb, LK, (long)LQ * LK, 0,
            nullptr, DK, 0.125f, 0);
        softmaxP_kernel<false><<<B_ * LQ, 256, 0, stream>>>(Sfb, Dfb, Sfb, meanOut, 1, h > 0 ? 1 : 0);
        dim3 gC2(1, LQ / 64, B_);
        gemm64<false><<<gC2, 256, 0, stream>>>(
            Sfb, LK, (long)LQ * LK, 0,
            vbuf + h * DK, DM, (long)LK * DM, 0,
            ctxbuf + h * DK, DM, (long)LQ * DM, 0,
            nullptr, LK, 1.0f, 0);
    }
    dim3 gO(DM / 64, (B_ * LQ) / 64, 1);
    gemm64<true><<<gO, 256, 0, stream>>>(ctxbuf, DM, 0, 0, Wo, DM, 0, 0,
                                         out, DM, 0, 0, bo, DM, 1.0f, 0);
}